// Round 1
// 1158.301 us; speedup vs baseline: 1.0114x; 1.0114x over previous
//
#include <hip/hip_runtime.h>
#include <hip/hip_bf16.h>
#include <hip/hip_fp16.h>

// Shapes: L=S=1024, N=8, H=8, E=512, Dh=64, B=N*H=64, scaling=1/8.
// ALL inputs fp32 (per reference dtypes); d_out fp32:
//   [attn_output (L,N,E) | avg_w (N,L,S)] = 12,582,912 floats.
// Internal pipeline: fp16 MFMA (16x16x32), fp32 accumulate.
//
// Round 1 changes vs baseline (1171 us):
//  - qk_pos runs FIRST and is write-only (no scattered 2MiB-stride RMW);
//    qk_content now adds into sbuf (local 2KiB-stride RMW, amortized by GEMM).
//  - pv_pos stages pos_v[l] via LDS transposed to [d][s] (+72-stride pad) so
//    B-fragments are ds_read_b128 instead of 16 scalar 4B global gathers.
//  - softmax_avg loads/stores f16x8 instead of 16 scalar fp16 accesses.
//  - 3 projection GEMMs fused into one launch (blockIdx.z).

typedef float     f32x4  __attribute__((ext_vector_type(4)));
typedef _Float16  f16x8  __attribute__((ext_vector_type(8)));

#define MFMA_F16  __builtin_amdgcn_mfma_f32_16x16x32_f16

__device__ __forceinline__ f16x8 ld8f(const float* __restrict__ p){
  const f32x4 a = *(const f32x4*)p;
  const f32x4 b = *(const f32x4*)(p + 4);
  f16x8 h;
#pragma unroll
  for (int t = 0; t < 4; ++t) { h[t] = (_Float16)a[t]; h[t + 4] = (_Float16)b[t]; }
  return h;
}

// ---------------------------------------------------------------------------
// K1 (fused x3): C[m,i] = (sum_j X[m,j]*W[i,j] + bias[i]) * scale
// z=0: query->qb (scale=0.125, mode0)  z=1: key->kb  z=2: value->vT (mode1)
// mode 0: out[m*512+i] fp16;  mode 1: out[b*65536 + d*1024 + s] fp16
// ---------------------------------------------------------------------------
__global__ __launch_bounds__(256) void proj_all(
    const float* __restrict__ Xq, const float* __restrict__ Xk, const float* __restrict__ Xv,
    const float* __restrict__ Wq, const float* __restrict__ Wk, const float* __restrict__ Wv,
    const float* __restrict__ bq, const float* __restrict__ bk, const float* __restrict__ bv,
    _Float16* __restrict__ qb, _Float16* __restrict__ kb, _Float16* __restrict__ vT)
{
  const int which = blockIdx.z;
  const float* X    = (which == 0) ? Xq : (which == 1) ? Xk : Xv;
  const float* W    = (which == 0) ? Wq : (which == 1) ? Wk : Wv;
  const float* bias = (which == 0) ? bq : (which == 1) ? bk : bv;
  _Float16*   out   = (which == 0) ? qb : (which == 1) ? kb : vT;
  const float scale = (which == 0) ? 0.125f : 1.0f;
  const int   mode  = (which == 2) ? 1 : 0;

  const int tid = threadIdx.x, wave = tid >> 6, lane = tid & 63;
  const int lrow = lane & 15, quad = lane >> 4;
  const int m_base = blockIdx.x * 64 + (wave >> 1) * 32;
  const int n_base = blockIdx.y * 64 + (wave & 1) * 32;
  f32x4 acc[2][2] = {};
#pragma unroll 2
  for (int k0 = 0; k0 < 512; k0 += 32) {
    const int ko = k0 + quad * 8;
    f16x8 a0 = ld8f(X + (size_t)(m_base + lrow) * 512 + ko);
    f16x8 a1 = ld8f(X + (size_t)(m_base + 16 + lrow) * 512 + ko);
    f16x8 b0 = ld8f(W + (size_t)(n_base + lrow) * 512 + ko);
    f16x8 b1 = ld8f(W + (size_t)(n_base + 16 + lrow) * 512 + ko);
    acc[0][0] = MFMA_F16(a0, b0, acc[0][0], 0, 0, 0);
    acc[0][1] = MFMA_F16(a0, b1, acc[0][1], 0, 0, 0);
    acc[1][0] = MFMA_F16(a1, b0, acc[1][0], 0, 0, 0);
    acc[1][1] = MFMA_F16(a1, b1, acc[1][1], 0, 0, 0);
  }
#pragma unroll
  for (int i = 0; i < 2; ++i)
#pragma unroll
  for (int j = 0; j < 2; ++j) {
    const int ncol = n_base + j * 16 + lrow;
    const float bv2 = bias[ncol];
#pragma unroll
    for (int r = 0; r < 4; ++r) {
      const int m = m_base + i * 16 + quad * 4 + r;
      const float val = (acc[i][j][r] + bv2) * scale;
      if (mode == 0) {
        out[(size_t)m * 512 + ncol] = (_Float16)val;
      } else {
        const int s = m >> 3, nn = m & 7, h = ncol >> 6, d = ncol & 63;
        out[(size_t)(nn * 8 + h) * 65536 + (size_t)d * 1024 + s] = (_Float16)val;
      }
    }
  }
}

// ---------------------------------------------------------------------------
// K8: out0[m,i] = sum_j ctx2[m,j]*Wo[i,j] + bo[i]   (fp32 out)
// ---------------------------------------------------------------------------
__global__ __launch_bounds__(256) void out_gemm(
    const _Float16* __restrict__ X, const float* __restrict__ W,
    const float* __restrict__ bias, float* __restrict__ out)
{
  const int tid = threadIdx.x, wave = tid >> 6, lane = tid & 63;
  const int lrow = lane & 15, quad = lane >> 4;
  const int m_base = blockIdx.x * 64 + (wave >> 1) * 32;
  const int n_base = blockIdx.y * 64 + (wave & 1) * 32;
  f32x4 acc[2][2] = {};
#pragma unroll 2
  for (int k0 = 0; k0 < 512; k0 += 32) {
    const int ko = k0 + quad * 8;
    f16x8 a0 = *(const f16x8*)(X + (size_t)(m_base + lrow) * 512 + ko);
    f16x8 a1 = *(const f16x8*)(X + (size_t)(m_base + 16 + lrow) * 512 + ko);
    f16x8 b0 = ld8f(W + (size_t)(n_base + lrow) * 512 + ko);
    f16x8 b1 = ld8f(W + (size_t)(n_base + 16 + lrow) * 512 + ko);
    acc[0][0] = MFMA_F16(a0, b0, acc[0][0], 0, 0, 0);
    acc[0][1] = MFMA_F16(a0, b1, acc[0][1], 0, 0, 0);
    acc[1][0] = MFMA_F16(a1, b0, acc[1][0], 0, 0, 0);
    acc[1][1] = MFMA_F16(a1, b1, acc[1][1], 0, 0, 0);
  }
#pragma unroll
  for (int i = 0; i < 2; ++i)
#pragma unroll
  for (int j = 0; j < 2; ++j) {
    const int ncol = n_base + j * 16 + lrow;
    const float bv2 = bias[ncol];
#pragma unroll
    for (int r = 0; r < 4; ++r) {
      const int m = m_base + i * 16 + quad * 4 + r;
      out[(size_t)m * 512 + ncol] = acc[i][j][r] + bv2;
    }
  }
}

// ---------------------------------------------------------------------------
// K3 (now first): pos scores per l: sbuf[b,l,s] = sum_d q[l,b,d]*pos_k[l,s,d]
// WRITE-ONLY (content term added later by qk_content).
// ---------------------------------------------------------------------------
__global__ __launch_bounds__(256) void qk_pos(
    const _Float16* __restrict__ qb, const float* __restrict__ pk,
    _Float16* __restrict__ sbuf)
{
  const int l = blockIdx.x;
  const int tid = threadIdx.x, wave = tid >> 6, lane = tid & 63;
  const int lrow = lane & 15, quad = lane >> 4;
  const int b_base = (wave >> 1) * 32;
  const int s_base = blockIdx.y * 64 + (wave & 1) * 32;
  const _Float16* qp = qb + (size_t)l * 4096;
  const float* pp = pk + (size_t)l * 65536;
  f32x4 acc[2][2] = {};
#pragma unroll
  for (int k0 = 0; k0 < 64; k0 += 32) {
    const int ko = k0 + quad * 8;
    f16x8 a0 = *(const f16x8*)(qp + (size_t)(b_base + lrow) * 64 + ko);
    f16x8 a1 = *(const f16x8*)(qp + (size_t)(b_base + 16 + lrow) * 64 + ko);
    f16x8 b0 = ld8f(pp + (size_t)(s_base + lrow) * 64 + ko);
    f16x8 b1 = ld8f(pp + (size_t)(s_base + 16 + lrow) * 64 + ko);
    acc[0][0] = MFMA_F16(a0, b0, acc[0][0], 0, 0, 0);
    acc[0][1] = MFMA_F16(a0, b1, acc[0][1], 0, 0, 0);
    acc[1][0] = MFMA_F16(a1, b0, acc[1][0], 0, 0, 0);
    acc[1][1] = MFMA_F16(a1, b1, acc[1][1], 0, 0, 0);
  }
#pragma unroll
  for (int i = 0; i < 2; ++i)
#pragma unroll
  for (int j = 0; j < 2; ++j)
#pragma unroll
  for (int r = 0; r < 4; ++r) {
    const size_t idx = (size_t)(b_base + i * 16 + quad * 4 + r) * 1048576 +
                       (size_t)l * 1024 + s_base + j * 16 + lrow;
    sbuf[idx] = (_Float16)acc[i][j][r];
  }
}

// ---------------------------------------------------------------------------
// K2 (now second): content scores per b: sbuf[b,l,s] += sum_d q[l,b,d]*k[s,b,d]
// RMW is local (2KiB-stride within a 128KiB window), amortized by the GEMM.
// ---------------------------------------------------------------------------
__global__ __launch_bounds__(256) void qk_content(
    const _Float16* __restrict__ qb, const _Float16* __restrict__ kb,
    _Float16* __restrict__ sbuf)
{
  const int b = blockIdx.z;
  const int tid = threadIdx.x, wave = tid >> 6, lane = tid & 63;
  const int lrow = lane & 15, quad = lane >> 4;
  const int l_base = blockIdx.x * 64 + (wave >> 1) * 32;
  const int s_base = blockIdx.y * 64 + (wave & 1) * 32;
  const _Float16* qp = qb + b * 64;
  const _Float16* kp = kb + b * 64;
  f32x4 acc[2][2] = {};
#pragma unroll
  for (int k0 = 0; k0 < 64; k0 += 32) {
    const int ko = k0 + quad * 8;
    f16x8 a0 = *(const f16x8*)(qp + (size_t)(l_base + lrow) * 4096 + ko);
    f16x8 a1 = *(const f16x8*)(qp + (size_t)(l_base + 16 + lrow) * 4096 + ko);
    f16x8 b0 = *(const f16x8*)(kp + (size_t)(s_base + lrow) * 4096 + ko);
    f16x8 b1 = *(const f16x8*)(kp + (size_t)(s_base + 16 + lrow) * 4096 + ko);
    acc[0][0] = MFMA_F16(a0, b0, acc[0][0], 0, 0, 0);
    acc[0][1] = MFMA_F16(a0, b1, acc[0][1], 0, 0, 0);
    acc[1][0] = MFMA_F16(a1, b0, acc[1][0], 0, 0, 0);
    acc[1][1] = MFMA_F16(a1, b1, acc[1][1], 0, 0, 0);
  }
  _Float16* sp = sbuf + (size_t)b * 1048576;
#pragma unroll
  for (int i = 0; i < 2; ++i)
#pragma unroll
  for (int j = 0; j < 2; ++j)
#pragma unroll
  for (int r = 0; r < 4; ++r) {
    const size_t idx = (size_t)(l_base + i * 16 + quad * 4 + r) * 1024 +
                       s_base + j * 16 + lrow;
    sp[idx] = (_Float16)((float)sp[idx] + acc[i][j][r]);
  }
}

// ---------------------------------------------------------------------------
// K4: per (n,l): softmax over s for all 8 heads (one wave each), write w fp16
//     back in place; avg over heads -> fp32 avg_w output. f16x8 vectorized.
// ---------------------------------------------------------------------------
__global__ __launch_bounds__(512) void softmax_avg(
    _Float16* __restrict__ sbuf, float* __restrict__ avg_out)
{
  __shared__ _Float16 lds[8 * 1088];
  const int bx = blockIdx.x;
  const int n = bx >> 10, l = bx & 1023;
  const int tid = threadIdx.x, h = tid >> 6, lane = tid & 63;
  _Float16* row = sbuf + (size_t)(n * 8 + h) * 1048576 + (size_t)l * 1024;
  const f16x8 r0 = *(const f16x8*)(row + lane * 8);
  const f16x8 r1 = *(const f16x8*)(row + 512 + lane * 8);
  float x[16];
#pragma unroll
  for (int t = 0; t < 8; ++t) { x[t] = (float)r0[t]; x[8 + t] = (float)r1[t]; }
  float m = x[0];
#pragma unroll
  for (int i = 1; i < 16; ++i) m = fmaxf(m, x[i]);
#pragma unroll
  for (int off = 32; off > 0; off >>= 1) m = fmaxf(m, __shfl_xor(m, off));
  float z = 0.f;
#pragma unroll
  for (int i = 0; i < 16; ++i) { x[i] = __expf(x[i] - m); z += x[i]; }
#pragma unroll
  for (int off = 32; off > 0; off >>= 1) z += __shfl_xor(z, off);
  const float inv = 1.0f / z;
  f16x8 w0, w1;
#pragma unroll
  for (int t = 0; t < 8; ++t) {
    w0[t] = (_Float16)(x[t] * inv);
    w1[t] = (_Float16)(x[8 + t] * inv);
  }
  *(f16x8*)(row + lane * 8) = w0;
  *(f16x8*)(row + 512 + lane * 8) = w1;
  *(f16x8*)(&lds[h * 1088 + lane * 8]) = w0;
  *(f16x8*)(&lds[h * 1088 + 512 + lane * 8]) = w1;
  __syncthreads();
  float* ao = avg_out + (size_t)n * 1048576 + (size_t)l * 1024;
  for (int s = tid; s < 1024; s += 512) {
    float acc = 0.f;
#pragma unroll
    for (int h2 = 0; h2 < 8; ++h2) acc += (float)lds[h2 * 1088 + s];
    ao[s] = acc * 0.125f;
  }
}

// ---------------------------------------------------------------------------
// K6: content PV per b: ctx[l, b*64+d] = sum_s w[b,l,s]*v[b,s,d]  (fp32)
// ---------------------------------------------------------------------------
__global__ __launch_bounds__(256) void pv_content(
    const _Float16* __restrict__ sbuf, const _Float16* __restrict__ vT,
    float* __restrict__ ctx)
{
  const int b = blockIdx.x;
  const int tid = threadIdx.x, wave = tid >> 6, lane = tid & 63;
  const int lrow = lane & 15, quad = lane >> 4;
  const int l_base = blockIdx.y * 64 + (wave >> 1) * 32;
  const int d_base = (wave & 1) * 32;
  const _Float16* wp = sbuf + (size_t)b * 1048576;
  const _Float16* vp = vT + (size_t)b * 65536;
  f32x4 acc[2][2] = {};
  for (int s0 = 0; s0 < 1024; s0 += 32) {
    const int so = s0 + quad * 8;
    f16x8 a0 = *(const f16x8*)(wp + (size_t)(l_base + lrow) * 1024 + so);
    f16x8 a1 = *(const f16x8*)(wp + (size_t)(l_base + 16 + lrow) * 1024 + so);
    f16x8 b0 = *(const f16x8*)(vp + (size_t)(d_base + lrow) * 1024 + so);
    f16x8 b1 = *(const f16x8*)(vp + (size_t)(d_base + 16 + lrow) * 1024 + so);
    acc[0][0] = MFMA_F16(a0, b0, acc[0][0], 0, 0, 0);
    acc[0][1] = MFMA_F16(a0, b1, acc[0][1], 0, 0, 0);
    acc[1][0] = MFMA_F16(a1, b0, acc[1][0], 0, 0, 0);
    acc[1][1] = MFMA_F16(a1, b1, acc[1][1], 0, 0, 0);
  }
#pragma unroll
  for (int i = 0; i < 2; ++i)
#pragma unroll
  for (int j = 0; j < 2; ++j)
#pragma unroll
  for (int r = 0; r < 4; ++r)
    ctx[(size_t)(l_base + i * 16 + quad * 4 + r) * 4096 + b * 64 + d_base + j * 16 + lrow] =
        acc[i][j][r];
}

// ---------------------------------------------------------------------------
// K7: pos PV per l: ctx2[l, b*64+d] = fp16(ctx + sum_s w[b,l,s]*pos_v[l,s,d])
// pos_v staged through LDS transposed [d][s] (stride 72) -> B frags are
// ds_read_b128 instead of 16 scalar 4B global gathers per fragment.
// ---------------------------------------------------------------------------
__global__ __launch_bounds__(256) void pv_pos(
    const _Float16* __restrict__ sbuf, const float* __restrict__ pv,
    const float* __restrict__ ctx, _Float16* __restrict__ ctx2)
{
  __shared__ _Float16 lds[64][72];   // [d][s_chunk], +8 pad breaks 128B stride
  const int l = blockIdx.x;
  const int tid = threadIdx.x, wave = tid >> 6, lane = tid & 63;
  const int lrow = lane & 15, quad = lane >> 4;
  const int b_base = (wave >> 1) * 32;
  const int d_base = (wave & 1) * 32;
  const float* pp = pv + (size_t)l * 65536;
  const _Float16* wp = sbuf + (size_t)l * 1024;
  // staging mapping: thread -> (s row, 16-wide d chunk)
  const int st_s = tid >> 2, st_d = (tid & 3) * 16;
  f32x4 acc[2][2] = {};
  for (int s0 = 0; s0 < 1024; s0 += 64) {
    __syncthreads();   // previous chunk's readers done before overwrite
    const float* src = pp + (size_t)(s0 + st_s) * 64 + st_d;
    const f32x4 va = *(const f32x4*)src;
    const f32x4 vb = *(const f32x4*)(src + 4);
    const f32x4 vc = *(const f32x4*)(src + 8);
    const f32x4 vd = *(const f32x4*)(src + 12);
#pragma unroll
    for (int u = 0; u < 4; ++u) {
      lds[st_d + u     ][st_s] = (_Float16)va[u];
      lds[st_d + u + 4 ][st_s] = (_Float16)vb[u];
      lds[st_d + u + 8 ][st_s] = (_Float16)vc[u];
      lds[st_d + u + 12][st_s] = (_Float16)vd[u];
    }
    __syncthreads();
#pragma unroll
    for (int k0 = 0; k0 < 64; k0 += 32) {
      const int so = s0 + k0 + quad * 8;   // global s for A (w rows)
      const int sl = k0 + quad * 8;        // local s for B (lds)
      f16x8 a0 = *(const f16x8*)(wp + (size_t)(b_base + lrow) * 1048576 + so);
      f16x8 a1 = *(const f16x8*)(wp + (size_t)(b_base + 16 + lrow) * 1048576 + so);
      f16x8 b0 = *(const f16x8*)(&lds[d_base + lrow][sl]);
      f16x8 b1 = *(const f16x8*)(&lds[d_base + 16 + lrow][sl]);
      acc[0][0] = MFMA_F16(a0, b0, acc[0][0], 0, 0, 0);
      acc[0][1] = MFMA_F16(a0, b1, acc[0][1], 0, 0, 0);
      acc[1][0] = MFMA_F16(a1, b0, acc[1][0], 0, 0, 0);
      acc[1][1] = MFMA_F16(a1, b1, acc[1][1], 0, 0, 0);
    }
  }
#pragma unroll
  for (int i = 0; i < 2; ++i)
#pragma unroll
  for (int j = 0; j < 2; ++j)
#pragma unroll
  for (int r = 0; r < 4; ++r) {
    const size_t idx = (size_t)l * 4096 + (size_t)(b_base + i * 16 + quad * 4 + r) * 64 +
                       d_base + j * 16 + lrow;
    ctx2[idx] = (_Float16)(ctx[idx] + acc[i][j][r]);
  }
}

// ---------------------------------------------------------------------------
extern "C" void kernel_launch(void* const* d_in, const int* in_sizes, int n_in,
                              void* d_out, int out_size, void* d_ws, size_t ws_size,
                              hipStream_t stream)
{
  const float* query = (const float*)d_in[0];
  const float* key   = (const float*)d_in[1];
  const float* value = (const float*)d_in[2];
  const float* pos_k = (const float*)d_in[3];
  const float* pos_v = (const float*)d_in[4];
  const float* Wq = (const float*)d_in[5];
  const float* bq = (const float*)d_in[6];
  const float* Wk = (const float*)d_in[7];
  const float* bk = (const float*)d_in[8];
  const float* Wv = (const float*)d_in[9];
  const float* bv = (const float*)d_in[10];
  const float* Wo = (const float*)d_in[11];
  const float* bo = (const float*)d_in[12];

  char* ws = (char*)d_ws;
  _Float16* qb   = (_Float16*)(ws);                        // 8 MiB  [l][b*64+d]
  _Float16* kb   = (_Float16*)(ws + (size_t)(8u  << 20));  // 8 MiB  [s][b*64+d]
  _Float16* vT   = (_Float16*)(ws + (size_t)(16u << 20));  // 8 MiB  [b][d][s]
  _Float16* sbuf = (_Float16*)(ws + (size_t)(24u << 20));  // 128 MiB [b][l][s]
  float*    ctx  = (float*)   (ws + (size_t)(152u << 20)); // 16 MiB [l][b*64+d]
  _Float16* ctx2 = (_Float16*)(ws + (size_t)(168u << 20)); // 8 MiB  [l][b*64+d]

  float* out0 = (float*)d_out;
  float* avg  = out0 + (size_t)4194304;

  dim3 blk(256);
  proj_all<<<dim3(128, 8, 3), blk, 0, stream>>>(query, key, value,
                                                Wq, Wk, Wv, bq, bk, bv,
                                                qb, kb, vT);
  qk_pos<<<dim3(1024, 16), blk, 0, stream>>>(qb, pos_k, sbuf);          // write
  qk_content<<<dim3(16, 16, 64), blk, 0, stream>>>(qb, kb, sbuf);       // add
  softmax_avg<<<dim3(8192), dim3(512), 0, stream>>>(sbuf, avg);
  pv_content<<<dim3(64, 16), blk, 0, stream>>>(sbuf, vT, ctx);
  pv_pos<<<dim3(1024), blk, 0, stream>>>(sbuf, pos_v, ctx, ctx2);
  out_gemm<<<dim3(128, 8), blk, 0, stream>>>(ctx2, Wo, bo, out0);
}

// Round 2
// 1000.466 us; speedup vs baseline: 1.1710x; 1.1578x over previous
//
#include <hip/hip_runtime.h>
#include <hip/hip_bf16.h>
#include <hip/hip_fp16.h>

// Shapes: L=S=1024, N=8, H=8, E=512, Dh=64, B=N*H=64, scaling=1/8.
// ALL inputs fp32 (per reference dtypes); d_out fp32:
//   [attn_output (L,N,E) | avg_w (N,L,S)] = 12,582,912 floats.
// Internal pipeline: fp16 MFMA (16x16x32), fp32 accumulate.
//
// Round 2 changes vs round 1 (1158 us):
//  - proj_all / out_gemm rewritten as LDS-staged 128x128-tile GEMMs:
//    4 waves x 64x64 quadrant, BK=32, fp16 LDS tiles [128][40] (80B row
//    stride: 16B-aligned b128 reads, bank spread at the 8-words/bank floor),
//    register prefetch of k-step t+1 issued before MFMAs of step t.
//    Round-1 version was latency-bound (MfmaUtil 2.3%, VALUBusy 5.5%,
//    HBM 4.7%, 32 VGPR -> no in-flight loads).

typedef float     f32x4  __attribute__((ext_vector_type(4)));
typedef _Float16  f16x8  __attribute__((ext_vector_type(8)));

#define MFMA_F16  __builtin_amdgcn_mfma_f32_16x16x32_f16

__device__ __forceinline__ f16x8 ld8f(const float* __restrict__ p){
  const f32x4 a = *(const f32x4*)p;
  const f32x4 b = *(const f32x4*)(p + 4);
  f16x8 h;
#pragma unroll
  for (int t = 0; t < 4; ++t) { h[t] = (_Float16)a[t]; h[t + 4] = (_Float16)b[t]; }
  return h;
}

__device__ __forceinline__ f16x8 cvt8(f32x4 a, f32x4 b){
  f16x8 h;
#pragma unroll
  for (int t = 0; t < 4; ++t) { h[t] = (_Float16)a[t]; h[t + 4] = (_Float16)b[t]; }
  return h;
}

// ---------------------------------------------------------------------------
// K1 (fused x3, LDS-staged): C[m,i] = (sum_j X[m,j]*W[i,j] + bias[i]) * scale
// z=0: query->qb (scale=0.125, mode0)  z=1: key->kb  z=2: value->vT (mode1)
// mode 0: out[m*512+i] fp16;  mode 1: out[b*65536 + d*1024 + s] fp16
// Tile 128x128, BK=32, 4 waves (2x2 quadrants of 64x64), reg-prefetch k+1.
// ---------------------------------------------------------------------------
__global__ __launch_bounds__(256) void proj_all(
    const float* __restrict__ Xq, const float* __restrict__ Xk, const float* __restrict__ Xv,
    const float* __restrict__ Wq, const float* __restrict__ Wk, const float* __restrict__ Wv,
    const float* __restrict__ bq, const float* __restrict__ bk, const float* __restrict__ bv,
    _Float16* __restrict__ qb, _Float16* __restrict__ kb, _Float16* __restrict__ vT)
{
  __shared__ _Float16 As[128][40];   // 32 + 8 pad -> 80 B row stride
  __shared__ _Float16 Bs[128][40];

  const int which = blockIdx.z;
  const float* X    = (which == 0) ? Xq : (which == 1) ? Xk : Xv;
  const float* W    = (which == 0) ? Wq : (which == 1) ? Wk : Wv;
  const float* bias = (which == 0) ? bq : (which == 1) ? bk : bv;
  _Float16*   out   = (which == 0) ? qb : (which == 1) ? kb : vT;
  const float scale = (which == 0) ? 0.125f : 1.0f;
  const int   mode  = (which == 2) ? 1 : 0;

  const int tid = threadIdx.x, wave = tid >> 6, lane = tid & 63;
  const int lrow = lane & 15, quad = lane >> 4;
  const int wr = wave >> 1, wc = wave & 1;
  const int m_base = blockIdx.x * 128;
  const int n_base = blockIdx.y * 128;
  const int srow = tid >> 2, scol = (tid & 3) * 8;   // staging map

  const float* xp0 = X + (size_t)(m_base + srow)      * 512 + scol;
  const float* xp1 = X + (size_t)(m_base + 64 + srow) * 512 + scol;
  const float* wp0 = W + (size_t)(n_base + srow)      * 512 + scol;
  const float* wp1 = W + (size_t)(n_base + 64 + srow) * 512 + scol;

  f32x4 ra0, ra1, rb0, rb1, rc0, rc1, rd0, rd1;
  auto LOADK = [&](int k0) {
    ra0 = *(const f32x4*)(xp0 + k0);  ra1 = *(const f32x4*)(xp0 + k0 + 4);
    rb0 = *(const f32x4*)(xp1 + k0);  rb1 = *(const f32x4*)(xp1 + k0 + 4);
    rc0 = *(const f32x4*)(wp0 + k0);  rc1 = *(const f32x4*)(wp0 + k0 + 4);
    rd0 = *(const f32x4*)(wp1 + k0);  rd1 = *(const f32x4*)(wp1 + k0 + 4);
  };

  f32x4 acc[4][4] = {};
  LOADK(0);
  for (int k0 = 0; k0 < 512; k0 += 32) {
    __syncthreads();   // previous iteration's LDS readers done
    *(f16x8*)&As[srow][scol]      = cvt8(ra0, ra1);
    *(f16x8*)&As[srow + 64][scol] = cvt8(rb0, rb1);
    *(f16x8*)&Bs[srow][scol]      = cvt8(rc0, rc1);
    *(f16x8*)&Bs[srow + 64][scol] = cvt8(rd0, rd1);
    __syncthreads();
    if (k0 + 32 < 512) LOADK(k0 + 32);   // hide global latency under MFMAs
    f16x8 af[4], bf[4];
#pragma unroll
    for (int mi = 0; mi < 4; ++mi)
      af[mi] = *(const f16x8*)&As[wr * 64 + mi * 16 + lrow][quad * 8];
#pragma unroll
    for (int ni = 0; ni < 4; ++ni)
      bf[ni] = *(const f16x8*)&Bs[wc * 64 + ni * 16 + lrow][quad * 8];
#pragma unroll
    for (int mi = 0; mi < 4; ++mi)
#pragma unroll
      for (int ni = 0; ni < 4; ++ni)
        acc[mi][ni] = MFMA_F16(af[mi], bf[ni], acc[mi][ni], 0, 0, 0);
  }

#pragma unroll
  for (int mi = 0; mi < 4; ++mi)
#pragma unroll
  for (int ni = 0; ni < 4; ++ni) {
    const int ncol = n_base + wc * 64 + ni * 16 + lrow;
    const float bv2 = bias[ncol];
#pragma unroll
    for (int r = 0; r < 4; ++r) {
      const int m = m_base + wr * 64 + mi * 16 + quad * 4 + r;
      const float val = (acc[mi][ni][r] + bv2) * scale;
      if (mode == 0) {
        out[(size_t)m * 512 + ncol] = (_Float16)val;
      } else {
        const int s = m >> 3, nn = m & 7, h = ncol >> 6, d = ncol & 63;
        out[(size_t)(nn * 8 + h) * 65536 + (size_t)d * 1024 + s] = (_Float16)val;
      }
    }
  }
}

// ---------------------------------------------------------------------------
// K8 (LDS-staged): out0[m,i] = sum_j ctx2[m,j]*Wo[i,j] + bo[i]   (fp32 out)
// Same structure as proj_all; A operand is fp16 already.
// ---------------------------------------------------------------------------
__global__ __launch_bounds__(256) void out_gemm(
    const _Float16* __restrict__ X, const float* __restrict__ W,
    const float* __restrict__ bias, float* __restrict__ out)
{
  __shared__ _Float16 As[128][40];
  __shared__ _Float16 Bs[128][40];

  const int tid = threadIdx.x, wave = tid >> 6, lane = tid & 63;
  const int lrow = lane & 15, quad = lane >> 4;
  const int wr = wave >> 1, wc = wave & 1;
  const int m_base = blockIdx.x * 128;
  const int n_base = blockIdx.y * 128;
  const int srow = tid >> 2, scol = (tid & 3) * 8;

  const _Float16* xp0 = X + (size_t)(m_base + srow)      * 512 + scol;
  const _Float16* xp1 = X + (size_t)(m_base + 64 + srow) * 512 + scol;
  const float*    wp0 = W + (size_t)(n_base + srow)      * 512 + scol;
  const float*    wp1 = W + (size_t)(n_base + 64 + srow) * 512 + scol;

  f16x8 ha, hb; f32x4 rc0, rc1, rd0, rd1;
  auto LOADK = [&](int k0) {
    ha  = *(const f16x8*)(xp0 + k0);
    hb  = *(const f16x8*)(xp1 + k0);
    rc0 = *(const f32x4*)(wp0 + k0);  rc1 = *(const f32x4*)(wp0 + k0 + 4);
    rd0 = *(const f32x4*)(wp1 + k0);  rd1 = *(const f32x4*)(wp1 + k0 + 4);
  };

  f32x4 acc[4][4] = {};
  LOADK(0);
  for (int k0 = 0; k0 < 512; k0 += 32) {
    __syncthreads();
    *(f16x8*)&As[srow][scol]      = ha;
    *(f16x8*)&As[srow + 64][scol] = hb;
    *(f16x8*)&Bs[srow][scol]      = cvt8(rc0, rc1);
    *(f16x8*)&Bs[srow + 64][scol] = cvt8(rd0, rd1);
    __syncthreads();
    if (k0 + 32 < 512) LOADK(k0 + 32);
    f16x8 af[4], bf[4];
#pragma unroll
    for (int mi = 0; mi < 4; ++mi)
      af[mi] = *(const f16x8*)&As[wr * 64 + mi * 16 + lrow][quad * 8];
#pragma unroll
    for (int ni = 0; ni < 4; ++ni)
      bf[ni] = *(const f16x8*)&Bs[wc * 64 + ni * 16 + lrow][quad * 8];
#pragma unroll
    for (int mi = 0; mi < 4; ++mi)
#pragma unroll
      for (int ni = 0; ni < 4; ++ni)
        acc[mi][ni] = MFMA_F16(af[mi], bf[ni], acc[mi][ni], 0, 0, 0);
  }

#pragma unroll
  for (int mi = 0; mi < 4; ++mi)
#pragma unroll
  for (int ni = 0; ni < 4; ++ni) {
    const int ncol = n_base + wc * 64 + ni * 16 + lrow;
    const float bv2 = bias[ncol];
#pragma unroll
    for (int r = 0; r < 4; ++r) {
      const int m = m_base + wr * 64 + mi * 16 + quad * 4 + r;
      out[(size_t)m * 512 + ncol] = acc[mi][ni][r] + bv2;
    }
  }
}

// ---------------------------------------------------------------------------
// K3 (first): pos scores per l: sbuf[b,l,s] = sum_d q[l,b,d]*pos_k[l,s,d]
// WRITE-ONLY (content term added later by qk_content).
// ---------------------------------------------------------------------------
__global__ __launch_bounds__(256) void qk_pos(
    const _Float16* __restrict__ qb, const float* __restrict__ pk,
    _Float16* __restrict__ sbuf)
{
  const int l = blockIdx.x;
  const int tid = threadIdx.x, wave = tid >> 6, lane = tid & 63;
  const int lrow = lane & 15, quad = lane >> 4;
  const int b_base = (wave >> 1) * 32;
  const int s_base = blockIdx.y * 64 + (wave & 1) * 32;
  const _Float16* qp = qb + (size_t)l * 4096;
  const float* pp = pk + (size_t)l * 65536;
  f32x4 acc[2][2] = {};
#pragma unroll
  for (int k0 = 0; k0 < 64; k0 += 32) {
    const int ko = k0 + quad * 8;
    f16x8 a0 = *(const f16x8*)(qp + (size_t)(b_base + lrow) * 64 + ko);
    f16x8 a1 = *(const f16x8*)(qp + (size_t)(b_base + 16 + lrow) * 64 + ko);
    f16x8 b0 = ld8f(pp + (size_t)(s_base + lrow) * 64 + ko);
    f16x8 b1 = ld8f(pp + (size_t)(s_base + 16 + lrow) * 64 + ko);
    acc[0][0] = MFMA_F16(a0, b0, acc[0][0], 0, 0, 0);
    acc[0][1] = MFMA_F16(a0, b1, acc[0][1], 0, 0, 0);
    acc[1][0] = MFMA_F16(a1, b0, acc[1][0], 0, 0, 0);
    acc[1][1] = MFMA_F16(a1, b1, acc[1][1], 0, 0, 0);
  }
#pragma unroll
  for (int i = 0; i < 2; ++i)
#pragma unroll
  for (int j = 0; j < 2; ++j)
#pragma unroll
  for (int r = 0; r < 4; ++r) {
    const size_t idx = (size_t)(b_base + i * 16 + quad * 4 + r) * 1048576 +
                       (size_t)l * 1024 + s_base + j * 16 + lrow;
    sbuf[idx] = (_Float16)acc[i][j][r];
  }
}

// ---------------------------------------------------------------------------
// K2 (second): content scores per b: sbuf[b,l,s] += sum_d q[l,b,d]*k[s,b,d]
// ---------------------------------------------------------------------------
__global__ __launch_bounds__(256) void qk_content(
    const _Float16* __restrict__ qb, const _Float16* __restrict__ kb,
    _Float16* __restrict__ sbuf)
{
  const int b = blockIdx.z;
  const int tid = threadIdx.x, wave = tid >> 6, lane = tid & 63;
  const int lrow = lane & 15, quad = lane >> 4;
  const int l_base = blockIdx.x * 64 + (wave >> 1) * 32;
  const int s_base = blockIdx.y * 64 + (wave & 1) * 32;
  const _Float16* qp = qb + b * 64;
  const _Float16* kp = kb + b * 64;
  f32x4 acc[2][2] = {};
#pragma unroll
  for (int k0 = 0; k0 < 64; k0 += 32) {
    const int ko = k0 + quad * 8;
    f16x8 a0 = *(const f16x8*)(qp + (size_t)(l_base + lrow) * 4096 + ko);
    f16x8 a1 = *(const f16x8*)(qp + (size_t)(l_base + 16 + lrow) * 4096 + ko);
    f16x8 b0 = *(const f16x8*)(kp + (size_t)(s_base + lrow) * 4096 + ko);
    f16x8 b1 = *(const f16x8*)(kp + (size_t)(s_base + 16 + lrow) * 4096 + ko);
    acc[0][0] = MFMA_F16(a0, b0, acc[0][0], 0, 0, 0);
    acc[0][1] = MFMA_F16(a0, b1, acc[0][1], 0, 0, 0);
    acc[1][0] = MFMA_F16(a1, b0, acc[1][0], 0, 0, 0);
    acc[1][1] = MFMA_F16(a1, b1, acc[1][1], 0, 0, 0);
  }
  _Float16* sp = sbuf + (size_t)b * 1048576;
#pragma unroll
  for (int i = 0; i < 2; ++i)
#pragma unroll
  for (int j = 0; j < 2; ++j)
#pragma unroll
  for (int r = 0; r < 4; ++r) {
    const size_t idx = (size_t)(l_base + i * 16 + quad * 4 + r) * 1024 +
                       s_base + j * 16 + lrow;
    sp[idx] = (_Float16)((float)sp[idx] + acc[i][j][r]);
  }
}

// ---------------------------------------------------------------------------
// K4: per (n,l): softmax over s for all 8 heads (one wave each), write w fp16
//     back in place; avg over heads -> fp32 avg_w output. f16x8 vectorized.
// ---------------------------------------------------------------------------
__global__ __launch_bounds__(512) void softmax_avg(
    _Float16* __restrict__ sbuf, float* __restrict__ avg_out)
{
  __shared__ _Float16 lds[8 * 1088];
  const int bx = blockIdx.x;
  const int n = bx >> 10, l = bx & 1023;
  const int tid = threadIdx.x, h = tid >> 6, lane = tid & 63;
  _Float16* row = sbuf + (size_t)(n * 8 + h) * 1048576 + (size_t)l * 1024;
  const f16x8 r0 = *(const f16x8*)(row + lane * 8);
  const f16x8 r1 = *(const f16x8*)(row + 512 + lane * 8);
  float x[16];
#pragma unroll
  for (int t = 0; t < 8; ++t) { x[t] = (float)r0[t]; x[8 + t] = (float)r1[t]; }
  float m = x[0];
#pragma unroll
  for (int i = 1; i < 16; ++i) m = fmaxf(m, x[i]);
#pragma unroll
  for (int off = 32; off > 0; off >>= 1) m = fmaxf(m, __shfl_xor(m, off));
  float z = 0.f;
#pragma unroll
  for (int i = 0; i < 16; ++i) { x[i] = __expf(x[i] - m); z += x[i]; }
#pragma unroll
  for (int off = 32; off > 0; off >>= 1) z += __shfl_xor(z, off);
  const float inv = 1.0f / z;
  f16x8 w0, w1;
#pragma unroll
  for (int t = 0; t < 8; ++t) {
    w0[t] = (_Float16)(x[t] * inv);
    w1[t] = (_Float16)(x[8 + t] * inv);
  }
  *(f16x8*)(row + lane * 8) = w0;
  *(f16x8*)(row + 512 + lane * 8) = w1;
  *(f16x8*)(&lds[h * 1088 + lane * 8]) = w0;
  *(f16x8*)(&lds[h * 1088 + 512 + lane * 8]) = w1;
  __syncthreads();
  float* ao = avg_out + (size_t)n * 1048576 + (size_t)l * 1024;
  for (int s = tid; s < 1024; s += 512) {
    float acc = 0.f;
#pragma unroll
    for (int h2 = 0; h2 < 8; ++h2) acc += (float)lds[h2 * 1088 + s];
    ao[s] = acc * 0.125f;
  }
}

// ---------------------------------------------------------------------------
// K6: content PV per b: ctx[l, b*64+d] = sum_s w[b,l,s]*v[b,s,d]  (fp32)
// ---------------------------------------------------------------------------
__global__ __launch_bounds__(256) void pv_content(
    const _Float16* __restrict__ sbuf, const _Float16* __restrict__ vT,
    float* __restrict__ ctx)
{
  const int b = blockIdx.x;
  const int tid = threadIdx.x, wave = tid >> 6, lane = tid & 63;
  const int lrow = lane & 15, quad = lane >> 4;
  const int l_base = blockIdx.y * 64 + (wave >> 1) * 32;
  const int d_base = (wave & 1) * 32;
  const _Float16* wp = sbuf + (size_t)b * 1048576;
  const _Float16* vp = vT + (size_t)b * 65536;
  f32x4 acc[2][2] = {};
  for (int s0 = 0; s0 < 1024; s0 += 32) {
    const int so = s0 + quad * 8;
    f16x8 a0 = *(const f16x8*)(wp + (size_t)(l_base + lrow) * 1024 + so);
    f16x8 a1 = *(const f16x8*)(wp + (size_t)(l_base + 16 + lrow) * 1024 + so);
    f16x8 b0 = *(const f16x8*)(vp + (size_t)(d_base + lrow) * 1024 + so);
    f16x8 b1 = *(const f16x8*)(vp + (size_t)(d_base + 16 + lrow) * 1024 + so);
    acc[0][0] = MFMA_F16(a0, b0, acc[0][0], 0, 0, 0);
    acc[0][1] = MFMA_F16(a0, b1, acc[0][1], 0, 0, 0);
    acc[1][0] = MFMA_F16(a1, b0, acc[1][0], 0, 0, 0);
    acc[1][1] = MFMA_F16(a1, b1, acc[1][1], 0, 0, 0);
  }
#pragma unroll
  for (int i = 0; i < 2; ++i)
#pragma unroll
  for (int j = 0; j < 2; ++j)
#pragma unroll
  for (int r = 0; r < 4; ++r)
    ctx[(size_t)(l_base + i * 16 + quad * 4 + r) * 4096 + b * 64 + d_base + j * 16 + lrow] =
        acc[i][j][r];
}

// ---------------------------------------------------------------------------
// K7: pos PV per l: ctx2[l, b*64+d] = fp16(ctx + sum_s w[b,l,s]*pos_v[l,s,d])
// pos_v staged through LDS transposed [d][s] (stride 72).
// ---------------------------------------------------------------------------
__global__ __launch_bounds__(256) void pv_pos(
    const _Float16* __restrict__ sbuf, const float* __restrict__ pv,
    const float* __restrict__ ctx, _Float16* __restrict__ ctx2)
{
  __shared__ _Float16 lds[64][72];
  const int l = blockIdx.x;
  const int tid = threadIdx.x, wave = tid >> 6, lane = tid & 63;
  const int lrow = lane & 15, quad = lane >> 4;
  const int b_base = (wave >> 1) * 32;
  const int d_base = (wave & 1) * 32;
  const float* pp = pv + (size_t)l * 65536;
  const _Float16* wp = sbuf + (size_t)l * 1024;
  const int st_s = tid >> 2, st_d = (tid & 3) * 16;
  f32x4 acc[2][2] = {};
  for (int s0 = 0; s0 < 1024; s0 += 64) {
    __syncthreads();
    const float* src = pp + (size_t)(s0 + st_s) * 64 + st_d;
    const f32x4 va = *(const f32x4*)src;
    const f32x4 vb = *(const f32x4*)(src + 4);
    const f32x4 vc = *(const f32x4*)(src + 8);
    const f32x4 vd = *(const f32x4*)(src + 12);
#pragma unroll
    for (int u = 0; u < 4; ++u) {
      lds[st_d + u     ][st_s] = (_Float16)va[u];
      lds[st_d + u + 4 ][st_s] = (_Float16)vb[u];
      lds[st_d + u + 8 ][st_s] = (_Float16)vc[u];
      lds[st_d + u + 12][st_s] = (_Float16)vd[u];
    }
    __syncthreads();
#pragma unroll
    for (int k0 = 0; k0 < 64; k0 += 32) {
      const int so = s0 + k0 + quad * 8;
      const int sl = k0 + quad * 8;
      f16x8 a0 = *(const f16x8*)(wp + (size_t)(b_base + lrow) * 1048576 + so);
      f16x8 a1 = *(const f16x8*)(wp + (size_t)(b_base + 16 + lrow) * 1048576 + so);
      f16x8 b0 = *(const f16x8*)(&lds[d_base + lrow][sl]);
      f16x8 b1 = *(const f16x8*)(&lds[d_base + 16 + lrow][sl]);
      acc[0][0] = MFMA_F16(a0, b0, acc[0][0], 0, 0, 0);
      acc[0][1] = MFMA_F16(a0, b1, acc[0][1], 0, 0, 0);
      acc[1][0] = MFMA_F16(a1, b0, acc[1][0], 0, 0, 0);
      acc[1][1] = MFMA_F16(a1, b1, acc[1][1], 0, 0, 0);
    }
  }
#pragma unroll
  for (int i = 0; i < 2; ++i)
#pragma unroll
  for (int j = 0; j < 2; ++j)
#pragma unroll
  for (int r = 0; r < 4; ++r) {
    const size_t idx = (size_t)l * 4096 + (size_t)(b_base + i * 16 + quad * 4 + r) * 64 +
                       d_base + j * 16 + lrow;
    ctx2[idx] = (_Float16)(ctx[idx] + acc[i][j][r]);
  }
}

// ---------------------------------------------------------------------------
extern "C" void kernel_launch(void* const* d_in, const int* in_sizes, int n_in,
                              void* d_out, int out_size, void* d_ws, size_t ws_size,
                              hipStream_t stream)
{
  const float* query = (const float*)d_in[0];
  const float* key   = (const float*)d_in[1];
  const float* value = (const float*)d_in[2];
  const float* pos_k = (const float*)d_in[3];
  const float* pos_v = (const float*)d_in[4];
  const float* Wq = (const float*)d_in[5];
  const float* bq = (const float*)d_in[6];
  const float* Wk = (const float*)d_in[7];
  const float* bk = (const float*)d_in[8];
  const float* Wv = (const float*)d_in[9];
  const float* bv = (const float*)d_in[10];
  const float* Wo = (const float*)d_in[11];
  const float* bo = (const float*)d_in[12];

  char* ws = (char*)d_ws;
  _Float16* qb   = (_Float16*)(ws);                        // 8 MiB  [l][b*64+d]
  _Float16* kb   = (_Float16*)(ws + (size_t)(8u  << 20));  // 8 MiB  [s][b*64+d]
  _Float16* vT   = (_Float16*)(ws + (size_t)(16u << 20));  // 8 MiB  [b][d][s]
  _Float16* sbuf = (_Float16*)(ws + (size_t)(24u << 20));  // 128 MiB [b][l][s]
  float*    ctx  = (float*)   (ws + (size_t)(152u << 20)); // 16 MiB [l][b*64+d]
  _Float16* ctx2 = (_Float16*)(ws + (size_t)(168u << 20)); // 8 MiB  [l][b*64+d]

  float* out0 = (float*)d_out;
  float* avg  = out0 + (size_t)4194304;

  dim3 blk(256);
  proj_all<<<dim3(64, 4, 3), blk, 0, stream>>>(query, key, value,
                                               Wq, Wk, Wv, bq, bk, bv,
                                               qb, kb, vT);
  qk_pos<<<dim3(1024, 16), blk, 0, stream>>>(qb, pos_k, sbuf);          // write
  qk_content<<<dim3(16, 16, 64), blk, 0, stream>>>(qb, kb, sbuf);       // add
  softmax_avg<<<dim3(8192), dim3(512), 0, stream>>>(sbuf, avg);
  pv_content<<<dim3(64, 16), blk, 0, stream>>>(sbuf, vT, ctx);
  pv_pos<<<dim3(1024), blk, 0, stream>>>(sbuf, pos_v, ctx, ctx2);
  out_gemm<<<dim3(64, 4), blk, 0, stream>>>(ctx2, Wo, bo, out0);
}

// Round 3
// 956.827 us; speedup vs baseline: 1.2244x; 1.0456x over previous
//
#include <hip/hip_runtime.h>
#include <hip/hip_bf16.h>
#include <hip/hip_fp16.h>

// Shapes: L=S=1024, N=8, H=8, E=512, Dh=64, B=N*H=64, scaling=1/8.
// ALL inputs fp32 (per reference dtypes); d_out fp32:
//   [attn_output (L,N,E) | avg_w (N,L,S)] = 12,582,912 floats.
// Internal pipeline: fp16 MFMA (16x16x32), fp32 accumulate.
//
// Round 3 changes vs round 2 (1000 us):
//  - qk_pos restructured: one block per l (grid 1024), looping all 16 s-tiles
//    with register double-buffered prefetch of pos_k (8x f32x4 ping-pong);
//    Q fragments loaded once per block. Round-2 version was latency-bound
//    (MfmaUtil 1.7%, HBM 20%, 8 MFMAs/block, cold pos_k load feeding MFMA
//    directly with no overlap).

typedef float     f32x4  __attribute__((ext_vector_type(4)));
typedef _Float16  f16x8  __attribute__((ext_vector_type(8)));

#define MFMA_F16  __builtin_amdgcn_mfma_f32_16x16x32_f16

__device__ __forceinline__ f16x8 ld8f(const float* __restrict__ p){
  const f32x4 a = *(const f32x4*)p;
  const f32x4 b = *(const f32x4*)(p + 4);
  f16x8 h;
#pragma unroll
  for (int t = 0; t < 4; ++t) { h[t] = (_Float16)a[t]; h[t + 4] = (_Float16)b[t]; }
  return h;
}

__device__ __forceinline__ f16x8 cvt8(f32x4 a, f32x4 b){
  f16x8 h;
#pragma unroll
  for (int t = 0; t < 4; ++t) { h[t] = (_Float16)a[t]; h[t + 4] = (_Float16)b[t]; }
  return h;
}

// ---------------------------------------------------------------------------
// K1 (fused x3, LDS-staged): C[m,i] = (sum_j X[m,j]*W[i,j] + bias[i]) * scale
// z=0: query->qb (scale=0.125, mode0)  z=1: key->kb  z=2: value->vT (mode1)
// ---------------------------------------------------------------------------
__global__ __launch_bounds__(256) void proj_all(
    const float* __restrict__ Xq, const float* __restrict__ Xk, const float* __restrict__ Xv,
    const float* __restrict__ Wq, const float* __restrict__ Wk, const float* __restrict__ Wv,
    const float* __restrict__ bq, const float* __restrict__ bk, const float* __restrict__ bv,
    _Float16* __restrict__ qb, _Float16* __restrict__ kb, _Float16* __restrict__ vT)
{
  __shared__ _Float16 As[128][40];   // 32 + 8 pad -> 80 B row stride
  __shared__ _Float16 Bs[128][40];

  const int which = blockIdx.z;
  const float* X    = (which == 0) ? Xq : (which == 1) ? Xk : Xv;
  const float* W    = (which == 0) ? Wq : (which == 1) ? Wk : Wv;
  const float* bias = (which == 0) ? bq : (which == 1) ? bk : bv;
  _Float16*   out   = (which == 0) ? qb : (which == 1) ? kb : vT;
  const float scale = (which == 0) ? 0.125f : 1.0f;
  const int   mode  = (which == 2) ? 1 : 0;

  const int tid = threadIdx.x, wave = tid >> 6, lane = tid & 63;
  const int lrow = lane & 15, quad = lane >> 4;
  const int wr = wave >> 1, wc = wave & 1;
  const int m_base = blockIdx.x * 128;
  const int n_base = blockIdx.y * 128;
  const int srow = tid >> 2, scol = (tid & 3) * 8;   // staging map

  const float* xp0 = X + (size_t)(m_base + srow)      * 512 + scol;
  const float* xp1 = X + (size_t)(m_base + 64 + srow) * 512 + scol;
  const float* wp0 = W + (size_t)(n_base + srow)      * 512 + scol;
  const float* wp1 = W + (size_t)(n_base + 64 + srow) * 512 + scol;

  f32x4 ra0, ra1, rb0, rb1, rc0, rc1, rd0, rd1;
  auto LOADK = [&](int k0) {
    ra0 = *(const f32x4*)(xp0 + k0);  ra1 = *(const f32x4*)(xp0 + k0 + 4);
    rb0 = *(const f32x4*)(xp1 + k0);  rb1 = *(const f32x4*)(xp1 + k0 + 4);
    rc0 = *(const f32x4*)(wp0 + k0);  rc1 = *(const f32x4*)(wp0 + k0 + 4);
    rd0 = *(const f32x4*)(wp1 + k0);  rd1 = *(const f32x4*)(wp1 + k0 + 4);
  };

  f32x4 acc[4][4] = {};
  LOADK(0);
  for (int k0 = 0; k0 < 512; k0 += 32) {
    __syncthreads();   // previous iteration's LDS readers done
    *(f16x8*)&As[srow][scol]      = cvt8(ra0, ra1);
    *(f16x8*)&As[srow + 64][scol] = cvt8(rb0, rb1);
    *(f16x8*)&Bs[srow][scol]      = cvt8(rc0, rc1);
    *(f16x8*)&Bs[srow + 64][scol] = cvt8(rd0, rd1);
    __syncthreads();
    if (k0 + 32 < 512) LOADK(k0 + 32);   // hide global latency under MFMAs
    f16x8 af[4], bf[4];
#pragma unroll
    for (int mi = 0; mi < 4; ++mi)
      af[mi] = *(const f16x8*)&As[wr * 64 + mi * 16 + lrow][quad * 8];
#pragma unroll
    for (int ni = 0; ni < 4; ++ni)
      bf[ni] = *(const f16x8*)&Bs[wc * 64 + ni * 16 + lrow][quad * 8];
#pragma unroll
    for (int mi = 0; mi < 4; ++mi)
#pragma unroll
      for (int ni = 0; ni < 4; ++ni)
        acc[mi][ni] = MFMA_F16(af[mi], bf[ni], acc[mi][ni], 0, 0, 0);
  }

#pragma unroll
  for (int mi = 0; mi < 4; ++mi)
#pragma unroll
  for (int ni = 0; ni < 4; ++ni) {
    const int ncol = n_base + wc * 64 + ni * 16 + lrow;
    const float bv2 = bias[ncol];
#pragma unroll
    for (int r = 0; r < 4; ++r) {
      const int m = m_base + wr * 64 + mi * 16 + quad * 4 + r;
      const float val = (acc[mi][ni][r] + bv2) * scale;
      if (mode == 0) {
        out[(size_t)m * 512 + ncol] = (_Float16)val;
      } else {
        const int s = m >> 3, nn = m & 7, h = ncol >> 6, d = ncol & 63;
        out[(size_t)(nn * 8 + h) * 65536 + (size_t)d * 1024 + s] = (_Float16)val;
      }
    }
  }
}

// ---------------------------------------------------------------------------
// K8 (LDS-staged): out0[m,i] = sum_j ctx2[m,j]*Wo[i,j] + bo[i]   (fp32 out)
// ---------------------------------------------------------------------------
__global__ __launch_bounds__(256) void out_gemm(
    const _Float16* __restrict__ X, const float* __restrict__ W,
    const float* __restrict__ bias, float* __restrict__ out)
{
  __shared__ _Float16 As[128][40];
  __shared__ _Float16 Bs[128][40];

  const int tid = threadIdx.x, wave = tid >> 6, lane = tid & 63;
  const int lrow = lane & 15, quad = lane >> 4;
  const int wr = wave >> 1, wc = wave & 1;
  const int m_base = blockIdx.x * 128;
  const int n_base = blockIdx.y * 128;
  const int srow = tid >> 2, scol = (tid & 3) * 8;

  const _Float16* xp0 = X + (size_t)(m_base + srow)      * 512 + scol;
  const _Float16* xp1 = X + (size_t)(m_base + 64 + srow) * 512 + scol;
  const float*    wp0 = W + (size_t)(n_base + srow)      * 512 + scol;
  const float*    wp1 = W + (size_t)(n_base + 64 + srow) * 512 + scol;

  f16x8 ha, hb; f32x4 rc0, rc1, rd0, rd1;
  auto LOADK = [&](int k0) {
    ha  = *(const f16x8*)(xp0 + k0);
    hb  = *(const f16x8*)(xp1 + k0);
    rc0 = *(const f32x4*)(wp0 + k0);  rc1 = *(const f32x4*)(wp0 + k0 + 4);
    rd0 = *(const f32x4*)(wp1 + k0);  rd1 = *(const f32x4*)(wp1 + k0 + 4);
  };

  f32x4 acc[4][4] = {};
  LOADK(0);
  for (int k0 = 0; k0 < 512; k0 += 32) {
    __syncthreads();
    *(f16x8*)&As[srow][scol]      = ha;
    *(f16x8*)&As[srow + 64][scol] = hb;
    *(f16x8*)&Bs[srow][scol]      = cvt8(rc0, rc1);
    *(f16x8*)&Bs[srow + 64][scol] = cvt8(rd0, rd1);
    __syncthreads();
    if (k0 + 32 < 512) LOADK(k0 + 32);
    f16x8 af[4], bf[4];
#pragma unroll
    for (int mi = 0; mi < 4; ++mi)
      af[mi] = *(const f16x8*)&As[wr * 64 + mi * 16 + lrow][quad * 8];
#pragma unroll
    for (int ni = 0; ni < 4; ++ni)
      bf[ni] = *(const f16x8*)&Bs[wc * 64 + ni * 16 + lrow][quad * 8];
#pragma unroll
    for (int mi = 0; mi < 4; ++mi)
#pragma unroll
      for (int ni = 0; ni < 4; ++ni)
        acc[mi][ni] = MFMA_F16(af[mi], bf[ni], acc[mi][ni], 0, 0, 0);
  }

#pragma unroll
  for (int mi = 0; mi < 4; ++mi)
#pragma unroll
  for (int ni = 0; ni < 4; ++ni) {
    const int ncol = n_base + wc * 64 + ni * 16 + lrow;
    const float bv2 = bias[ncol];
#pragma unroll
    for (int r = 0; r < 4; ++r) {
      const int m = m_base + wr * 64 + mi * 16 + quad * 4 + r;
      out[(size_t)m * 512 + ncol] = acc[mi][ni][r] + bv2;
    }
  }
}

// ---------------------------------------------------------------------------
// K3 (first): pos scores: sbuf[b,l,s] = sum_d q[l,b,d]*pos_k[l,s,d]
// One block per l; loops all 16 s-tiles with register double-buffer prefetch.
// Q fragments register-resident for the whole block. WRITE-ONLY.
// ---------------------------------------------------------------------------
__global__ __launch_bounds__(256) void qk_pos(
    const _Float16* __restrict__ qb, const float* __restrict__ pk,
    _Float16* __restrict__ sbuf)
{
  const int l = blockIdx.x;
  const int tid = threadIdx.x, wave = tid >> 6, lane = tid & 63;
  const int lrow = lane & 15, quad = lane >> 4;
  const int b_base = (wave >> 1) * 32;
  const int s_half = (wave & 1) * 32;
  const _Float16* qp = qb + (size_t)l * 4096;
  const float* pp = pk + (size_t)l * 65536;

  // Q fragments: constant across the whole s loop (K=64 -> 2 k-steps)
  f16x8 a[2][2];
#pragma unroll
  for (int ks = 0; ks < 2; ++ks) {
    const int ko = ks * 32 + quad * 8;
    a[ks][0] = *(const f16x8*)(qp + (size_t)(b_base + lrow) * 64 + ko);
    a[ks][1] = *(const f16x8*)(qp + (size_t)(b_base + 16 + lrow) * 64 + ko);
  }

  auto LOADS = [&](int s0, f32x4 (&buf)[8]) {
#pragma unroll
    for (int ks = 0; ks < 2; ++ks) {
      const int ko = ks * 32 + quad * 8;
      const float* r0 = pp + (size_t)(s0 + s_half + lrow) * 64 + ko;
      const float* r1 = r0 + 16 * 64;
      buf[ks * 4 + 0] = *(const f32x4*)r0;
      buf[ks * 4 + 1] = *(const f32x4*)(r0 + 4);
      buf[ks * 4 + 2] = *(const f32x4*)r1;
      buf[ks * 4 + 3] = *(const f32x4*)(r1 + 4);
    }
  };

  auto COMPUTE = [&](int s0, f32x4 (&buf)[8]) {
    f32x4 acc[2][2] = {};
#pragma unroll
    for (int ks = 0; ks < 2; ++ks) {
      const f16x8 b0 = cvt8(buf[ks * 4 + 0], buf[ks * 4 + 1]);
      const f16x8 b1 = cvt8(buf[ks * 4 + 2], buf[ks * 4 + 3]);
      acc[0][0] = MFMA_F16(a[ks][0], b0, acc[0][0], 0, 0, 0);
      acc[0][1] = MFMA_F16(a[ks][0], b1, acc[0][1], 0, 0, 0);
      acc[1][0] = MFMA_F16(a[ks][1], b0, acc[1][0], 0, 0, 0);
      acc[1][1] = MFMA_F16(a[ks][1], b1, acc[1][1], 0, 0, 0);
    }
#pragma unroll
    for (int i = 0; i < 2; ++i)
#pragma unroll
    for (int j = 0; j < 2; ++j)
#pragma unroll
    for (int r = 0; r < 4; ++r) {
      const size_t idx = (size_t)(b_base + i * 16 + quad * 4 + r) * 1048576 +
                         (size_t)l * 1024 + s0 + s_half + j * 16 + lrow;
      sbuf[idx] = (_Float16)acc[i][j][r];
    }
  };

  f32x4 bufA[8], bufB[8];
  LOADS(0, bufA);
  for (int s0 = 0; s0 < 1024; s0 += 128) {
    LOADS(s0 + 64, bufB);          // prefetch tile t+1 before computing t
    COMPUTE(s0, bufA);
    if (s0 + 128 < 1024) LOADS(s0 + 128, bufA);
    COMPUTE(s0 + 64, bufB);
  }
}

// ---------------------------------------------------------------------------
// K2 (second): content scores per b: sbuf[b,l,s] += sum_d q[l,b,d]*k[s,b,d]
// ---------------------------------------------------------------------------
__global__ __launch_bounds__(256) void qk_content(
    const _Float16* __restrict__ qb, const _Float16* __restrict__ kb,
    _Float16* __restrict__ sbuf)
{
  const int b = blockIdx.z;
  const int tid = threadIdx.x, wave = tid >> 6, lane = tid & 63;
  const int lrow = lane & 15, quad = lane >> 4;
  const int l_base = blockIdx.x * 64 + (wave >> 1) * 32;
  const int s_base = blockIdx.y * 64 + (wave & 1) * 32;
  const _Float16* qp = qb + b * 64;
  const _Float16* kp = kb + b * 64;
  f32x4 acc[2][2] = {};
#pragma unroll
  for (int k0 = 0; k0 < 64; k0 += 32) {
    const int ko = k0 + quad * 8;
    f16x8 a0 = *(const f16x8*)(qp + (size_t)(l_base + lrow) * 4096 + ko);
    f16x8 a1 = *(const f16x8*)(qp + (size_t)(l_base + 16 + lrow) * 4096 + ko);
    f16x8 b0 = *(const f16x8*)(kp + (size_t)(s_base + lrow) * 4096 + ko);
    f16x8 b1 = *(const f16x8*)(kp + (size_t)(s_base + 16 + lrow) * 4096 + ko);
    acc[0][0] = MFMA_F16(a0, b0, acc[0][0], 0, 0, 0);
    acc[0][1] = MFMA_F16(a0, b1, acc[0][1], 0, 0, 0);
    acc[1][0] = MFMA_F16(a1, b0, acc[1][0], 0, 0, 0);
    acc[1][1] = MFMA_F16(a1, b1, acc[1][1], 0, 0, 0);
  }
  _Float16* sp = sbuf + (size_t)b * 1048576;
#pragma unroll
  for (int i = 0; i < 2; ++i)
#pragma unroll
  for (int j = 0; j < 2; ++j)
#pragma unroll
  for (int r = 0; r < 4; ++r) {
    const size_t idx = (size_t)(l_base + i * 16 + quad * 4 + r) * 1024 +
                       s_base + j * 16 + lrow;
    sp[idx] = (_Float16)((float)sp[idx] + acc[i][j][r]);
  }
}

// ---------------------------------------------------------------------------
// K4: per (n,l): softmax over s for all 8 heads (one wave each), write w fp16
//     back in place; avg over heads -> fp32 avg_w output. f16x8 vectorized.
// ---------------------------------------------------------------------------
__global__ __launch_bounds__(512) void softmax_avg(
    _Float16* __restrict__ sbuf, float* __restrict__ avg_out)
{
  __shared__ _Float16 lds[8 * 1088];
  const int bx = blockIdx.x;
  const int n = bx >> 10, l = bx & 1023;
  const int tid = threadIdx.x, h = tid >> 6, lane = tid & 63;
  _Float16* row = sbuf + (size_t)(n * 8 + h) * 1048576 + (size_t)l * 1024;
  const f16x8 r0 = *(const f16x8*)(row + lane * 8);
  const f16x8 r1 = *(const f16x8*)(row + 512 + lane * 8);
  float x[16];
#pragma unroll
  for (int t = 0; t < 8; ++t) { x[t] = (float)r0[t]; x[8 + t] = (float)r1[t]; }
  float m = x[0];
#pragma unroll
  for (int i = 1; i < 16; ++i) m = fmaxf(m, x[i]);
#pragma unroll
  for (int off = 32; off > 0; off >>= 1) m = fmaxf(m, __shfl_xor(m, off));
  float z = 0.f;
#pragma unroll
  for (int i = 0; i < 16; ++i) { x[i] = __expf(x[i] - m); z += x[i]; }
#pragma unroll
  for (int off = 32; off > 0; off >>= 1) z += __shfl_xor(z, off);
  const float inv = 1.0f / z;
  f16x8 w0, w1;
#pragma unroll
  for (int t = 0; t < 8; ++t) {
    w0[t] = (_Float16)(x[t] * inv);
    w1[t] = (_Float16)(x[8 + t] * inv);
  }
  *(f16x8*)(row + lane * 8) = w0;
  *(f16x8*)(row + 512 + lane * 8) = w1;
  *(f16x8*)(&lds[h * 1088 + lane * 8]) = w0;
  *(f16x8*)(&lds[h * 1088 + 512 + lane * 8]) = w1;
  __syncthreads();
  float* ao = avg_out + (size_t)n * 1048576 + (size_t)l * 1024;
  for (int s = tid; s < 1024; s += 512) {
    float acc = 0.f;
#pragma unroll
    for (int h2 = 0; h2 < 8; ++h2) acc += (float)lds[h2 * 1088 + s];
    ao[s] = acc * 0.125f;
  }
}

// ---------------------------------------------------------------------------
// K6: content PV per b: ctx[l, b*64+d] = sum_s w[b,l,s]*v[b,s,d]  (fp32)
// ---------------------------------------------------------------------------
__global__ __launch_bounds__(256) void pv_content(
    const _Float16* __restrict__ sbuf, const _Float16* __restrict__ vT,
    float* __restrict__ ctx)
{
  const int b = blockIdx.x;
  const int tid = threadIdx.x, wave = tid >> 6, lane = tid & 63;
  const int lrow = lane & 15, quad = lane >> 4;
  const int l_base = blockIdx.y * 64 + (wave >> 1) * 32;
  const int d_base = (wave & 1) * 32;
  const _Float16* wp = sbuf + (size_t)b * 1048576;
  const _Float16* vp = vT + (size_t)b * 65536;
  f32x4 acc[2][2] = {};
  for (int s0 = 0; s0 < 1024; s0 += 32) {
    const int so = s0 + quad * 8;
    f16x8 a0 = *(const f16x8*)(wp + (size_t)(l_base + lrow) * 1024 + so);
    f16x8 a1 = *(const f16x8*)(wp + (size_t)(l_base + 16 + lrow) * 1024 + so);
    f16x8 b0 = *(const f16x8*)(vp + (size_t)(d_base + lrow) * 1024 + so);
    f16x8 b1 = *(const f16x8*)(vp + (size_t)(d_base + 16 + lrow) * 1024 + so);
    acc[0][0] = MFMA_F16(a0, b0, acc[0][0], 0, 0, 0);
    acc[0][1] = MFMA_F16(a0, b1, acc[0][1], 0, 0, 0);
    acc[1][0] = MFMA_F16(a1, b0, acc[1][0], 0, 0, 0);
    acc[1][1] = MFMA_F16(a1, b1, acc[1][1], 0, 0, 0);
  }
#pragma unroll
  for (int i = 0; i < 2; ++i)
#pragma unroll
  for (int j = 0; j < 2; ++j)
#pragma unroll
  for (int r = 0; r < 4; ++r)
    ctx[(size_t)(l_base + i * 16 + quad * 4 + r) * 4096 + b * 64 + d_base + j * 16 + lrow] =
        acc[i][j][r];
}

// ---------------------------------------------------------------------------
// K7: pos PV per l: ctx2[l, b*64+d] = fp16(ctx + sum_s w[b,l,s]*pos_v[l,s,d])
// pos_v staged through LDS transposed [d][s] (stride 72).
// ---------------------------------------------------------------------------
__global__ __launch_bounds__(256) void pv_pos(
    const _Float16* __restrict__ sbuf, const float* __restrict__ pv,
    const float* __restrict__ ctx, _Float16* __restrict__ ctx2)
{
  __shared__ _Float16 lds[64][72];
  const int l = blockIdx.x;
  const int tid = threadIdx.x, wave = tid >> 6, lane = tid & 63;
  const int lrow = lane & 15, quad = lane >> 4;
  const int b_base = (wave >> 1) * 32;
  const int d_base = (wave & 1) * 32;
  const float* pp = pv + (size_t)l * 65536;
  const _Float16* wp = sbuf + (size_t)l * 1024;
  const int st_s = tid >> 2, st_d = (tid & 3) * 16;
  f32x4 acc[2][2] = {};
  for (int s0 = 0; s0 < 1024; s0 += 64) {
    __syncthreads();
    const float* src = pp + (size_t)(s0 + st_s) * 64 + st_d;
    const f32x4 va = *(const f32x4*)src;
    const f32x4 vb = *(const f32x4*)(src + 4);
    const f32x4 vc = *(const f32x4*)(src + 8);
    const f32x4 vd = *(const f32x4*)(src + 12);
#pragma unroll
    for (int u = 0; u < 4; ++u) {
      lds[st_d + u     ][st_s] = (_Float16)va[u];
      lds[st_d + u + 4 ][st_s] = (_Float16)vb[u];
      lds[st_d + u + 8 ][st_s] = (_Float16)vc[u];
      lds[st_d + u + 12][st_s] = (_Float16)vd[u];
    }
    __syncthreads();
#pragma unroll
    for (int k0 = 0; k0 < 64; k0 += 32) {
      const int so = s0 + k0 + quad * 8;
      const int sl = k0 + quad * 8;
      f16x8 a0 = *(const f16x8*)(wp + (size_t)(b_base + lrow) * 1048576 + so);
      f16x8 a1 = *(const f16x8*)(wp + (size_t)(b_base + 16 + lrow) * 1048576 + so);
      f16x8 b0 = *(const f16x8*)(&lds[d_base + lrow][sl]);
      f16x8 b1 = *(const f16x8*)(&lds[d_base + 16 + lrow][sl]);
      acc[0][0] = MFMA_F16(a0, b0, acc[0][0], 0, 0, 0);
      acc[0][1] = MFMA_F16(a0, b1, acc[0][1], 0, 0, 0);
      acc[1][0] = MFMA_F16(a1, b0, acc[1][0], 0, 0, 0);
      acc[1][1] = MFMA_F16(a1, b1, acc[1][1], 0, 0, 0);
    }
  }
#pragma unroll
  for (int i = 0; i < 2; ++i)
#pragma unroll
  for (int j = 0; j < 2; ++j)
#pragma unroll
  for (int r = 0; r < 4; ++r) {
    const size_t idx = (size_t)l * 4096 + (size_t)(b_base + i * 16 + quad * 4 + r) * 64 +
                       d_base + j * 16 + lrow;
    ctx2[idx] = (_Float16)(ctx[idx] + acc[i][j][r]);
  }
}

// ---------------------------------------------------------------------------
extern "C" void kernel_launch(void* const* d_in, const int* in_sizes, int n_in,
                              void* d_out, int out_size, void* d_ws, size_t ws_size,
                              hipStream_t stream)
{
  const float* query = (const float*)d_in[0];
  const float* key   = (const float*)d_in[1];
  const float* value = (const float*)d_in[2];
  const float* pos_k = (const float*)d_in[3];
  const float* pos_v = (const float*)d_in[4];
  const float* Wq = (const float*)d_in[5];
  const float* bq = (const float*)d_in[6];
  const float* Wk = (const float*)d_in[7];
  const float* bk = (const float*)d_in[8];
  const float* Wv = (const float*)d_in[9];
  const float* bv = (const float*)d_in[10];
  const float* Wo = (const float*)d_in[11];
  const float* bo = (const float*)d_in[12];

  char* ws = (char*)d_ws;
  _Float16* qb   = (_Float16*)(ws);                        // 8 MiB  [l][b*64+d]
  _Float16* kb   = (_Float16*)(ws + (size_t)(8u  << 20));  // 8 MiB  [s][b*64+d]
  _Float16* vT   = (_Float16*)(ws + (size_t)(16u << 20));  // 8 MiB  [b][d][s]
  _Float16* sbuf = (_Float16*)(ws + (size_t)(24u << 20));  // 128 MiB [b][l][s]
  float*    ctx  = (float*)   (ws + (size_t)(152u << 20)); // 16 MiB [l][b*64+d]
  _Float16* ctx2 = (_Float16*)(ws + (size_t)(168u << 20)); // 8 MiB  [l][b*64+d]

  float* out0 = (float*)d_out;
  float* avg  = out0 + (size_t)4194304;

  dim3 blk(256);
  proj_all<<<dim3(64, 4, 3), blk, 0, stream>>>(query, key, value,
                                               Wq, Wk, Wv, bq, bk, bv,
                                               qb, kb, vT);
  qk_pos<<<dim3(1024), blk, 0, stream>>>(qb, pos_k, sbuf);              // write
  qk_content<<<dim3(16, 16, 64), blk, 0, stream>>>(qb, kb, sbuf);       // add
  softmax_avg<<<dim3(8192), dim3(512), 0, stream>>>(sbuf, avg);
  pv_content<<<dim3(64, 16), blk, 0, stream>>>(sbuf, vT, ctx);
  pv_pos<<<dim3(1024), blk, 0, stream>>>(sbuf, pos_v, ctx, ctx2);
  out_gemm<<<dim3(64, 4), blk, 0, stream>>>(ctx2, Wo, bo, out0);
}

// Round 4
// 954.349 us; speedup vs baseline: 1.2276x; 1.0026x over previous
//
#include <hip/hip_runtime.h>
#include <hip/hip_bf16.h>
#include <hip/hip_fp16.h>

// Shapes: L=S=1024, N=8, H=8, E=512, Dh=64, B=N*H=64, scaling=1/8.
// ALL inputs fp32 (per reference dtypes); d_out fp32:
//   [attn_output (L,N,E) | avg_w (N,L,S)] = 12,582,912 floats.
// Internal pipeline: fp16 MFMA (16x16x32), fp32 accumulate.
//
// Round 4 changes vs round 3 (957 us):
//  - sbuf relayout [b][l][s] -> [l][b][s] (contiguous 128 KB slice per l).
//  - qk_content is now WRITE-ONLY (RMW read eliminated).
//  - qk_pos + softmax_avg fused into pos_softmax_avg (block per (l, 32-b
//    half)): pos term via MFMA with A=pos_k rows / B=q rows so C[row=s,
//    col=b] puts a full s-run in each lane's registers; softmax reduce =
//    in-lane + 2 shfl_xor + small LDS combine across 4 s-quarter waves;
//    head-avg = 3 shfl_xor over the b-octet. Saves one full 128 MiB
//    sbuf read+write pass and two kernel launches.

typedef float     f32x4  __attribute__((ext_vector_type(4)));
typedef _Float16  f16x8  __attribute__((ext_vector_type(8)));
typedef _Float16  f16x4  __attribute__((ext_vector_type(4)));

#define MFMA_F16  __builtin_amdgcn_mfma_f32_16x16x32_f16

__device__ __forceinline__ f16x8 ld8f(const float* __restrict__ p){
  const f32x4 a = *(const f32x4*)p;
  const f32x4 b = *(const f32x4*)(p + 4);
  f16x8 h;
#pragma unroll
  for (int t = 0; t < 4; ++t) { h[t] = (_Float16)a[t]; h[t + 4] = (_Float16)b[t]; }
  return h;
}

__device__ __forceinline__ f16x8 cvt8(f32x4 a, f32x4 b){
  f16x8 h;
#pragma unroll
  for (int t = 0; t < 4; ++t) { h[t] = (_Float16)a[t]; h[t + 4] = (_Float16)b[t]; }
  return h;
}

// ---------------------------------------------------------------------------
// K1 (fused x3, LDS-staged): C[m,i] = (sum_j X[m,j]*W[i,j] + bias[i]) * scale
// z=0: query->qb (scale=0.125, mode0)  z=1: key->kb  z=2: value->vT (mode1)
// ---------------------------------------------------------------------------
__global__ __launch_bounds__(256) void proj_all(
    const float* __restrict__ Xq, const float* __restrict__ Xk, const float* __restrict__ Xv,
    const float* __restrict__ Wq, const float* __restrict__ Wk, const float* __restrict__ Wv,
    const float* __restrict__ bq, const float* __restrict__ bk, const float* __restrict__ bv,
    _Float16* __restrict__ qb, _Float16* __restrict__ kb, _Float16* __restrict__ vT)
{
  __shared__ _Float16 As[128][40];   // 32 + 8 pad -> 80 B row stride
  __shared__ _Float16 Bs[128][40];

  const int which = blockIdx.z;
  const float* X    = (which == 0) ? Xq : (which == 1) ? Xk : Xv;
  const float* W    = (which == 0) ? Wq : (which == 1) ? Wk : Wv;
  const float* bias = (which == 0) ? bq : (which == 1) ? bk : bv;
  _Float16*   out   = (which == 0) ? qb : (which == 1) ? kb : vT;
  const float scale = (which == 0) ? 0.125f : 1.0f;
  const int   mode  = (which == 2) ? 1 : 0;

  const int tid = threadIdx.x, wave = tid >> 6, lane = tid & 63;
  const int lrow = lane & 15, quad = lane >> 4;
  const int wr = wave >> 1, wc = wave & 1;
  const int m_base = blockIdx.x * 128;
  const int n_base = blockIdx.y * 128;
  const int srow = tid >> 2, scol = (tid & 3) * 8;   // staging map

  const float* xp0 = X + (size_t)(m_base + srow)      * 512 + scol;
  const float* xp1 = X + (size_t)(m_base + 64 + srow) * 512 + scol;
  const float* wp0 = W + (size_t)(n_base + srow)      * 512 + scol;
  const float* wp1 = W + (size_t)(n_base + 64 + srow) * 512 + scol;

  f32x4 ra0, ra1, rb0, rb1, rc0, rc1, rd0, rd1;
  auto LOADK = [&](int k0) {
    ra0 = *(const f32x4*)(xp0 + k0);  ra1 = *(const f32x4*)(xp0 + k0 + 4);
    rb0 = *(const f32x4*)(xp1 + k0);  rb1 = *(const f32x4*)(xp1 + k0 + 4);
    rc0 = *(const f32x4*)(wp0 + k0);  rc1 = *(const f32x4*)(wp0 + k0 + 4);
    rd0 = *(const f32x4*)(wp1 + k0);  rd1 = *(const f32x4*)(wp1 + k0 + 4);
  };

  f32x4 acc[4][4] = {};
  LOADK(0);
  for (int k0 = 0; k0 < 512; k0 += 32) {
    __syncthreads();   // previous iteration's LDS readers done
    *(f16x8*)&As[srow][scol]      = cvt8(ra0, ra1);
    *(f16x8*)&As[srow + 64][scol] = cvt8(rb0, rb1);
    *(f16x8*)&Bs[srow][scol]      = cvt8(rc0, rc1);
    *(f16x8*)&Bs[srow + 64][scol] = cvt8(rd0, rd1);
    __syncthreads();
    if (k0 + 32 < 512) LOADK(k0 + 32);   // hide global latency under MFMAs
    f16x8 af[4], bf[4];
#pragma unroll
    for (int mi = 0; mi < 4; ++mi)
      af[mi] = *(const f16x8*)&As[wr * 64 + mi * 16 + lrow][quad * 8];
#pragma unroll
    for (int ni = 0; ni < 4; ++ni)
      bf[ni] = *(const f16x8*)&Bs[wc * 64 + ni * 16 + lrow][quad * 8];
#pragma unroll
    for (int mi = 0; mi < 4; ++mi)
#pragma unroll
      for (int ni = 0; ni < 4; ++ni)
        acc[mi][ni] = MFMA_F16(af[mi], bf[ni], acc[mi][ni], 0, 0, 0);
  }

#pragma unroll
  for (int mi = 0; mi < 4; ++mi)
#pragma unroll
  for (int ni = 0; ni < 4; ++ni) {
    const int ncol = n_base + wc * 64 + ni * 16 + lrow;
    const float bv2 = bias[ncol];
#pragma unroll
    for (int r = 0; r < 4; ++r) {
      const int m = m_base + wr * 64 + mi * 16 + quad * 4 + r;
      const float val = (acc[mi][ni][r] + bv2) * scale;
      if (mode == 0) {
        out[(size_t)m * 512 + ncol] = (_Float16)val;
      } else {
        const int s = m >> 3, nn = m & 7, h = ncol >> 6, d = ncol & 63;
        out[(size_t)(nn * 8 + h) * 65536 + (size_t)d * 1024 + s] = (_Float16)val;
      }
    }
  }
}

// ---------------------------------------------------------------------------
// K8 (LDS-staged): out0[m,i] = sum_j ctx2[m,j]*Wo[i,j] + bo[i]   (fp32 out)
// ---------------------------------------------------------------------------
__global__ __launch_bounds__(256) void out_gemm(
    const _Float16* __restrict__ X, const float* __restrict__ W,
    const float* __restrict__ bias, float* __restrict__ out)
{
  __shared__ _Float16 As[128][40];
  __shared__ _Float16 Bs[128][40];

  const int tid = threadIdx.x, wave = tid >> 6, lane = tid & 63;
  const int lrow = lane & 15, quad = lane >> 4;
  const int wr = wave >> 1, wc = wave & 1;
  const int m_base = blockIdx.x * 128;
  const int n_base = blockIdx.y * 128;
  const int srow = tid >> 2, scol = (tid & 3) * 8;

  const _Float16* xp0 = X + (size_t)(m_base + srow)      * 512 + scol;
  const _Float16* xp1 = X + (size_t)(m_base + 64 + srow) * 512 + scol;
  const float*    wp0 = W + (size_t)(n_base + srow)      * 512 + scol;
  const float*    wp1 = W + (size_t)(n_base + 64 + srow) * 512 + scol;

  f16x8 ha, hb; f32x4 rc0, rc1, rd0, rd1;
  auto LOADK = [&](int k0) {
    ha  = *(const f16x8*)(xp0 + k0);
    hb  = *(const f16x8*)(xp1 + k0);
    rc0 = *(const f32x4*)(wp0 + k0);  rc1 = *(const f32x4*)(wp0 + k0 + 4);
    rd0 = *(const f32x4*)(wp1 + k0);  rd1 = *(const f32x4*)(wp1 + k0 + 4);
  };

  f32x4 acc[4][4] = {};
  LOADK(0);
  for (int k0 = 0; k0 < 512; k0 += 32) {
    __syncthreads();
    *(f16x8*)&As[srow][scol]      = ha;
    *(f16x8*)&As[srow + 64][scol] = hb;
    *(f16x8*)&Bs[srow][scol]      = cvt8(rc0, rc1);
    *(f16x8*)&Bs[srow + 64][scol] = cvt8(rd0, rd1);
    __syncthreads();
    if (k0 + 32 < 512) LOADK(k0 + 32);
    f16x8 af[4], bf[4];
#pragma unroll
    for (int mi = 0; mi < 4; ++mi)
      af[mi] = *(const f16x8*)&As[wr * 64 + mi * 16 + lrow][quad * 8];
#pragma unroll
    for (int ni = 0; ni < 4; ++ni)
      bf[ni] = *(const f16x8*)&Bs[wc * 64 + ni * 16 + lrow][quad * 8];
#pragma unroll
    for (int mi = 0; mi < 4; ++mi)
#pragma unroll
      for (int ni = 0; ni < 4; ++ni)
        acc[mi][ni] = MFMA_F16(af[mi], bf[ni], acc[mi][ni], 0, 0, 0);
  }

#pragma unroll
  for (int mi = 0; mi < 4; ++mi)
#pragma unroll
  for (int ni = 0; ni < 4; ++ni) {
    const int ncol = n_base + wc * 64 + ni * 16 + lrow;
    const float bv2 = bias[ncol];
#pragma unroll
    for (int r = 0; r < 4; ++r) {
      const int m = m_base + wr * 64 + mi * 16 + quad * 4 + r;
      out[(size_t)m * 512 + ncol] = acc[mi][ni][r] + bv2;
    }
  }
}

// ---------------------------------------------------------------------------
// K2: content scores per b: sbuf[l][b][s] = sum_d q[l,b,d]*k[s,b,d]
// WRITE-ONLY into new [l][b][s] layout (pos term added in fused kernel).
// ---------------------------------------------------------------------------
__global__ __launch_bounds__(256) void qk_content(
    const _Float16* __restrict__ qb, const _Float16* __restrict__ kb,
    _Float16* __restrict__ sbuf)
{
  const int b = blockIdx.z;
  const int tid = threadIdx.x, wave = tid >> 6, lane = tid & 63;
  const int lrow = lane & 15, quad = lane >> 4;
  const int l_base = blockIdx.x * 64 + (wave >> 1) * 32;
  const int s_base = blockIdx.y * 64 + (wave & 1) * 32;
  const _Float16* qp = qb + b * 64;
  const _Float16* kp = kb + b * 64;
  f32x4 acc[2][2] = {};
#pragma unroll
  for (int k0 = 0; k0 < 64; k0 += 32) {
    const int ko = k0 + quad * 8;
    f16x8 a0 = *(const f16x8*)(qp + (size_t)(l_base + lrow) * 4096 + ko);
    f16x8 a1 = *(const f16x8*)(qp + (size_t)(l_base + 16 + lrow) * 4096 + ko);
    f16x8 b0 = *(const f16x8*)(kp + (size_t)(s_base + lrow) * 4096 + ko);
    f16x8 b1 = *(const f16x8*)(kp + (size_t)(s_base + 16 + lrow) * 4096 + ko);
    acc[0][0] = MFMA_F16(a0, b0, acc[0][0], 0, 0, 0);
    acc[0][1] = MFMA_F16(a0, b1, acc[0][1], 0, 0, 0);
    acc[1][0] = MFMA_F16(a1, b0, acc[1][0], 0, 0, 0);
    acc[1][1] = MFMA_F16(a1, b1, acc[1][1], 0, 0, 0);
  }
#pragma unroll
  for (int i = 0; i < 2; ++i)
#pragma unroll
  for (int j = 0; j < 2; ++j)
#pragma unroll
  for (int r = 0; r < 4; ++r) {
    const size_t idx = (size_t)(l_base + i * 16 + quad * 4 + r) * 65536 +
                       (size_t)b * 1024 + s_base + j * 16 + lrow;
    sbuf[idx] = (_Float16)acc[i][j][r];
  }
}

// ---------------------------------------------------------------------------
// K3+K4 fused: per (l, 32-b half):
//   x[b,s] = sbuf[l][b][s] + sum_d q[l,b,d]*pos_k[l,s,d]
//   w = softmax_s(x) -> sbuf[l][b][s] fp16 ;  avg over heads -> avg_out
// 8 waves: wave = wb*4 + ws; wb: b-chunk of 16, ws: s-quarter of 256.
// MFMA with A=pos_k rows (s), B=q rows (b): C[row=s, col=b] -> each lane
// holds 64 s-values for one b. Softmax: in-lane + shfl_xor(16,32) +
// LDS combine over 4 ws-waves. Head-avg: shfl_xor(1,2,4) over b-octet.
// ---------------------------------------------------------------------------
__global__ __launch_bounds__(512, 4) void pos_softmax_avg(
    const _Float16* __restrict__ qb, const float* __restrict__ pk,
    _Float16* __restrict__ sbuf, float* __restrict__ avg_out)
{
  __shared__ float pmax[2][4][16];
  __shared__ float psum[2][4][16];

  const int l = blockIdx.x;
  const int bh = blockIdx.y;               // 0/1: which 32-b half
  const int tid = threadIdx.x, wave = tid >> 6, lane = tid & 63;
  const int lrow = lane & 15, quad = lane >> 4;
  const int wb = wave >> 2;                // 0..1 b-chunk-of-16
  const int ws = wave & 3;                 // 0..3 s-quarter
  const int b0 = bh * 32 + wb * 16;

  const _Float16* qp = qb + (size_t)l * 4096 + (size_t)b0 * 64;
  const float*    pp = pk + (size_t)l * 65536 + (size_t)(ws * 256) * 64;
  _Float16*       sp = sbuf + (size_t)l * 65536;

  // B fragments: q rows b0+lrow (constant over the s loop)
  f16x8 bq[2];
#pragma unroll
  for (int ks = 0; ks < 2; ++ks)
    bq[ks] = *(const f16x8*)(qp + (size_t)lrow * 64 + ks * 32 + quad * 8);

  // pos scores: 16 s-tiles of 16, accumulate C[row=s, col=b]
  f32x4 acc[16] = {};
#pragma unroll
  for (int t = 0; t < 16; ++t) {
#pragma unroll
    for (int ks = 0; ks < 2; ++ks) {
      const f16x8 a = ld8f(pp + (size_t)(t * 16 + lrow) * 64 + ks * 32 + quad * 8);
      acc[t] = MFMA_F16(a, bq[ks], acc[t], 0, 0, 0);
    }
  }

  // add content scores; lane's b = b0+lrow, s = ws*256 + t*16 + quad*4 + r
  const _Float16* crow = sp + (size_t)(b0 + lrow) * 1024 + ws * 256 + quad * 4;
#pragma unroll
  for (int t = 0; t < 16; ++t) {
    const f16x4 c = *(const f16x4*)(crow + t * 16);
#pragma unroll
    for (int r = 0; r < 4; ++r) acc[t][r] += (float)c[r];
  }

  // wave-partial max over this quarter's 256 s for column b
  float mw = acc[0][0];
#pragma unroll
  for (int t = 0; t < 16; ++t)
#pragma unroll
    for (int r = 0; r < 4; ++r) mw = fmaxf(mw, acc[t][r]);
  mw = fmaxf(mw, __shfl_xor(mw, 16));
  mw = fmaxf(mw, __shfl_xor(mw, 32));

  // p = exp(x - mw) in place; partial sum
  float zw = 0.f;
#pragma unroll
  for (int t = 0; t < 16; ++t)
#pragma unroll
    for (int r = 0; r < 4; ++r) { acc[t][r] = __expf(acc[t][r] - mw); zw += acc[t][r]; }
  zw += __shfl_xor(zw, 16);
  zw += __shfl_xor(zw, 32);

  if (lane < 16) { pmax[wb][ws][lrow] = mw; psum[wb][ws][lrow] = zw; }
  __syncthreads();

  // global max / sum across the 4 s-quarters
  float M = pmax[wb][0][lrow];
#pragma unroll
  for (int o = 1; o < 4; ++o) M = fmaxf(M, pmax[wb][o][lrow]);
  float Z = 0.f;
#pragma unroll
  for (int o = 0; o < 4; ++o) Z += psum[wb][o][lrow] * __expf(pmax[wb][o][lrow] - M);
  const float scl = __expf(mw - M) / Z;

  // normalize, write w fp16 back; head-avg via shfl over b-octet
  _Float16* wrow = sp + (size_t)(b0 + lrow) * 1024 + ws * 256 + quad * 4;
  const int n = (b0 + lrow) >> 3;
  float* ao = avg_out + (size_t)n * 1048576 + (size_t)l * 1024 + ws * 256 + quad * 4;
  const bool wr_avg = ((lane & 7) == 0);
#pragma unroll
  for (int t = 0; t < 16; ++t) {
    f16x4 wv; f32x4 av;
#pragma unroll
    for (int r = 0; r < 4; ++r) {
      const float w = acc[t][r] * scl;
      wv[r] = (_Float16)w;
      float hsum = w;
      hsum += __shfl_xor(hsum, 1);
      hsum += __shfl_xor(hsum, 2);
      hsum += __shfl_xor(hsum, 4);
      av[r] = hsum * 0.125f;
    }
    *(f16x4*)(wrow + t * 16) = wv;
    if (wr_avg) *(f32x4*)(ao + t * 16) = av;
  }
}

// ---------------------------------------------------------------------------
// K6: content PV per b: ctx[l, b*64+d] = sum_s w[l][b][s]*v[b,s,d]  (fp32)
// ---------------------------------------------------------------------------
__global__ __launch_bounds__(256) void pv_content(
    const _Float16* __restrict__ sbuf, const _Float16* __restrict__ vT,
    float* __restrict__ ctx)
{
  const int b = blockIdx.x;
  const int tid = threadIdx.x, wave = tid >> 6, lane = tid & 63;
  const int lrow = lane & 15, quad = lane >> 4;
  const int l_base = blockIdx.y * 64 + (wave >> 1) * 32;
  const int d_base = (wave & 1) * 32;
  const _Float16* wp = sbuf + (size_t)b * 1024;
  const _Float16* vp = vT + (size_t)b * 65536;
  f32x4 acc[2][2] = {};
  for (int s0 = 0; s0 < 1024; s0 += 32) {
    const int so = s0 + quad * 8;
    f16x8 a0 = *(const f16x8*)(wp + (size_t)(l_base + lrow) * 65536 + so);
    f16x8 a1 = *(const f16x8*)(wp + (size_t)(l_base + 16 + lrow) * 65536 + so);
    f16x8 b0 = *(const f16x8*)(vp + (size_t)(d_base + lrow) * 1024 + so);
    f16x8 b1 = *(const f16x8*)(vp + (size_t)(d_base + 16 + lrow) * 1024 + so);
    acc[0][0] = MFMA_F16(a0, b0, acc[0][0], 0, 0, 0);
    acc[0][1] = MFMA_F16(a0, b1, acc[0][1], 0, 0, 0);
    acc[1][0] = MFMA_F16(a1, b0, acc[1][0], 0, 0, 0);
    acc[1][1] = MFMA_F16(a1, b1, acc[1][1], 0, 0, 0);
  }
#pragma unroll
  for (int i = 0; i < 2; ++i)
#pragma unroll
  for (int j = 0; j < 2; ++j)
#pragma unroll
  for (int r = 0; r < 4; ++r)
    ctx[(size_t)(l_base + i * 16 + quad * 4 + r) * 4096 + b * 64 + d_base + j * 16 + lrow] =
        acc[i][j][r];
}

// ---------------------------------------------------------------------------
// K7: pos PV per l: ctx2[l, b*64+d] = fp16(ctx + sum_s w[l][b][s]*pos_v[l,s,d])
// pos_v staged through LDS transposed [d][s] (stride 72).
// ---------------------------------------------------------------------------
__global__ __launch_bounds__(256) void pv_pos(
    const _Float16* __restrict__ sbuf, const float* __restrict__ pv,
    const float* __restrict__ ctx, _Float16* __restrict__ ctx2)
{
  __shared__ _Float16 lds[64][72];
  const int l = blockIdx.x;
  const int tid = threadIdx.x, wave = tid >> 6, lane = tid & 63;
  const int lrow = lane & 15, quad = lane >> 4;
  const int b_base = (wave >> 1) * 32;
  const int d_base = (wave & 1) * 32;
  const float* pp = pv + (size_t)l * 65536;
  const _Float16* wp = sbuf + (size_t)l * 65536;
  const int st_s = tid >> 2, st_d = (tid & 3) * 16;
  f32x4 acc[2][2] = {};
  for (int s0 = 0; s0 < 1024; s0 += 64) {
    __syncthreads();
    const float* src = pp + (size_t)(s0 + st_s) * 64 + st_d;
    const f32x4 va = *(const f32x4*)src;
    const f32x4 vb = *(const f32x4*)(src + 4);
    const f32x4 vc = *(const f32x4*)(src + 8);
    const f32x4 vd = *(const f32x4*)(src + 12);
#pragma unroll
    for (int u = 0; u < 4; ++u) {
      lds[st_d + u     ][st_s] = (_Float16)va[u];
      lds[st_d + u + 4 ][st_s] = (_Float16)vb[u];
      lds[st_d + u + 8 ][st_s] = (_Float16)vc[u];
      lds[st_d + u + 12][st_s] = (_Float16)vd[u];
    }
    __syncthreads();
#pragma unroll
    for (int k0 = 0; k0 < 64; k0 += 32) {
      const int so = s0 + k0 + quad * 8;
      const int sl = k0 + quad * 8;
      f16x8 a0 = *(const f16x8*)(wp + (size_t)(b_base + lrow) * 1024 + so);
      f16x8 a1 = *(const f16x8*)(wp + (size_t)(b_base + 16 + lrow) * 1024 + so);
      f16x8 b0 = *(const f16x8*)(&lds[d_base + lrow][sl]);
      f16x8 b1 = *(const f16x8*)(&lds[d_base + 16 + lrow][sl]);
      acc[0][0] = MFMA_F16(a0, b0, acc[0][0], 0, 0, 0);
      acc[0][1] = MFMA_F16(a0, b1, acc[0][1], 0, 0, 0);
      acc[1][0] = MFMA_F16(a1, b0, acc[1][0], 0, 0, 0);
      acc[1][1] = MFMA_F16(a1, b1, acc[1][1], 0, 0, 0);
    }
  }
#pragma unroll
  for (int i = 0; i < 2; ++i)
#pragma unroll
  for (int j = 0; j < 2; ++j)
#pragma unroll
  for (int r = 0; r < 4; ++r) {
    const size_t idx = (size_t)l * 4096 + (size_t)(b_base + i * 16 + quad * 4 + r) * 64 +
                       d_base + j * 16 + lrow;
    ctx2[idx] = (_Float16)(ctx[idx] + acc[i][j][r]);
  }
}

// ---------------------------------------------------------------------------
extern "C" void kernel_launch(void* const* d_in, const int* in_sizes, int n_in,
                              void* d_out, int out_size, void* d_ws, size_t ws_size,
                              hipStream_t stream)
{
  const float* query = (const float*)d_in[0];
  const float* key   = (const float*)d_in[1];
  const float* value = (const float*)d_in[2];
  const float* pos_k = (const float*)d_in[3];
  const float* pos_v = (const float*)d_in[4];
  const float* Wq = (const float*)d_in[5];
  const float* bq = (const float*)d_in[6];
  const float* Wk = (const float*)d_in[7];
  const float* bk = (const float*)d_in[8];
  const float* Wv = (const float*)d_in[9];
  const float* bv = (const float*)d_in[10];
  const float* Wo = (const float*)d_in[11];
  const float* bo = (const float*)d_in[12];

  char* ws = (char*)d_ws;
  _Float16* qb   = (_Float16*)(ws);                        // 8 MiB  [l][b*64+d]
  _Float16* kb   = (_Float16*)(ws + (size_t)(8u  << 20));  // 8 MiB  [s][b*64+d]
  _Float16* vT   = (_Float16*)(ws + (size_t)(16u << 20));  // 8 MiB  [b][d][s]
  _Float16* sbuf = (_Float16*)(ws + (size_t)(24u << 20));  // 128 MiB [l][b][s]
  float*    ctx  = (float*)   (ws + (size_t)(152u << 20)); // 16 MiB [l][b*64+d]
  _Float16* ctx2 = (_Float16*)(ws + (size_t)(168u << 20)); // 8 MiB  [l][b*64+d]

  float* out0 = (float*)d_out;
  float* avg  = out0 + (size_t)4194304;

  dim3 blk(256);
  proj_all<<<dim3(64, 4, 3), blk, 0, stream>>>(query, key, value,
                                               Wq, Wk, Wv, bq, bk, bv,
                                               qb, kb, vT);
  qk_content<<<dim3(16, 16, 64), blk, 0, stream>>>(qb, kb, sbuf);       // write
  pos_softmax_avg<<<dim3(1024, 2), dim3(512), 0, stream>>>(qb, pos_k, sbuf, avg);
  pv_content<<<dim3(64, 16), blk, 0, stream>>>(sbuf, vT, ctx);
  pv_pos<<<dim3(1024), blk, 0, stream>>>(sbuf, pos_v, ctx, ctx2);
  out_gemm<<<dim3(64, 4), blk, 0, stream>>>(ctx2, Wo, bo, out0);
}

// Round 5
// 871.548 us; speedup vs baseline: 1.3442x; 1.0950x over previous
//
#include <hip/hip_runtime.h>
#include <hip/hip_bf16.h>
#include <hip/hip_fp16.h>

// Shapes: L=S=1024, N=8, H=8, E=512, Dh=64, B=N*H=64, scaling=1/8.
// ALL inputs fp32 (per reference dtypes); d_out fp32:
//   [attn_output (L,N,E) | avg_w (N,L,S)] = 12,582,912 floats.
// Internal pipeline: fp16 MFMA (16x16x32), fp32 accumulate.
//
// Round 5 changes vs round 4 (954 us):
//  - pos_softmax_avg: one block per l (grid 1024), all 64 b-columns in one
//    block. 8 waves x 128-s strips; acc[8 s-tiles][4 b-chunks]; content
//    scores loaded as MFMA C-in (fused add, overlaps with pos_k stream).
//    Round-4 version fetched pos_k TWICE (602 MB vs 390 ideal: the two
//    bh-half blocks of the same l were 1024 dispatch slots apart) and had
//    only 52 VGPRs of load window (37% HBM peak).

typedef float     f32x4  __attribute__((ext_vector_type(4)));
typedef _Float16  f16x8  __attribute__((ext_vector_type(8)));
typedef _Float16  f16x4  __attribute__((ext_vector_type(4)));

#define MFMA_F16  __builtin_amdgcn_mfma_f32_16x16x32_f16

__device__ __forceinline__ f16x8 ld8f(const float* __restrict__ p){
  const f32x4 a = *(const f32x4*)p;
  const f32x4 b = *(const f32x4*)(p + 4);
  f16x8 h;
#pragma unroll
  for (int t = 0; t < 4; ++t) { h[t] = (_Float16)a[t]; h[t + 4] = (_Float16)b[t]; }
  return h;
}

__device__ __forceinline__ f16x8 cvt8(f32x4 a, f32x4 b){
  f16x8 h;
#pragma unroll
  for (int t = 0; t < 4; ++t) { h[t] = (_Float16)a[t]; h[t + 4] = (_Float16)b[t]; }
  return h;
}

// ---------------------------------------------------------------------------
// K1 (fused x3, LDS-staged): C[m,i] = (sum_j X[m,j]*W[i,j] + bias[i]) * scale
// z=0: query->qb (scale=0.125, mode0)  z=1: key->kb  z=2: value->vT (mode1)
// ---------------------------------------------------------------------------
__global__ __launch_bounds__(256) void proj_all(
    const float* __restrict__ Xq, const float* __restrict__ Xk, const float* __restrict__ Xv,
    const float* __restrict__ Wq, const float* __restrict__ Wk, const float* __restrict__ Wv,
    const float* __restrict__ bq, const float* __restrict__ bk, const float* __restrict__ bv,
    _Float16* __restrict__ qb, _Float16* __restrict__ kb, _Float16* __restrict__ vT)
{
  __shared__ _Float16 As[128][40];   // 32 + 8 pad -> 80 B row stride
  __shared__ _Float16 Bs[128][40];

  const int which = blockIdx.z;
  const float* X    = (which == 0) ? Xq : (which == 1) ? Xk : Xv;
  const float* W    = (which == 0) ? Wq : (which == 1) ? Wk : Wv;
  const float* bias = (which == 0) ? bq : (which == 1) ? bk : bv;
  _Float16*   out   = (which == 0) ? qb : (which == 1) ? kb : vT;
  const float scale = (which == 0) ? 0.125f : 1.0f;
  const int   mode  = (which == 2) ? 1 : 0;

  const int tid = threadIdx.x, wave = tid >> 6, lane = tid & 63;
  const int lrow = lane & 15, quad = lane >> 4;
  const int wr = wave >> 1, wc = wave & 1;
  const int m_base = blockIdx.x * 128;
  const int n_base = blockIdx.y * 128;
  const int srow = tid >> 2, scol = (tid & 3) * 8;   // staging map

  const float* xp0 = X + (size_t)(m_base + srow)      * 512 + scol;
  const float* xp1 = X + (size_t)(m_base + 64 + srow) * 512 + scol;
  const float* wp0 = W + (size_t)(n_base + srow)      * 512 + scol;
  const float* wp1 = W + (size_t)(n_base + 64 + srow) * 512 + scol;

  f32x4 ra0, ra1, rb0, rb1, rc0, rc1, rd0, rd1;
  auto LOADK = [&](int k0) {
    ra0 = *(const f32x4*)(xp0 + k0);  ra1 = *(const f32x4*)(xp0 + k0 + 4);
    rb0 = *(const f32x4*)(xp1 + k0);  rb1 = *(const f32x4*)(xp1 + k0 + 4);
    rc0 = *(const f32x4*)(wp0 + k0);  rc1 = *(const f32x4*)(wp0 + k0 + 4);
    rd0 = *(const f32x4*)(wp1 + k0);  rd1 = *(const f32x4*)(wp1 + k0 + 4);
  };

  f32x4 acc[4][4] = {};
  LOADK(0);
  for (int k0 = 0; k0 < 512; k0 += 32) {
    __syncthreads();   // previous iteration's LDS readers done
    *(f16x8*)&As[srow][scol]      = cvt8(ra0, ra1);
    *(f16x8*)&As[srow + 64][scol] = cvt8(rb0, rb1);
    *(f16x8*)&Bs[srow][scol]      = cvt8(rc0, rc1);
    *(f16x8*)&Bs[srow + 64][scol] = cvt8(rd0, rd1);
    __syncthreads();
    if (k0 + 32 < 512) LOADK(k0 + 32);   // hide global latency under MFMAs
    f16x8 af[4], bf[4];
#pragma unroll
    for (int mi = 0; mi < 4; ++mi)
      af[mi] = *(const f16x8*)&As[wr * 64 + mi * 16 + lrow][quad * 8];
#pragma unroll
    for (int ni = 0; ni < 4; ++ni)
      bf[ni] = *(const f16x8*)&Bs[wc * 64 + ni * 16 + lrow][quad * 8];
#pragma unroll
    for (int mi = 0; mi < 4; ++mi)
#pragma unroll
      for (int ni = 0; ni < 4; ++ni)
        acc[mi][ni] = MFMA_F16(af[mi], bf[ni], acc[mi][ni], 0, 0, 0);
  }

#pragma unroll
  for (int mi = 0; mi < 4; ++mi)
#pragma unroll
  for (int ni = 0; ni < 4; ++ni) {
    const int ncol = n_base + wc * 64 + ni * 16 + lrow;
    const float bv2 = bias[ncol];
#pragma unroll
    for (int r = 0; r < 4; ++r) {
      const int m = m_base + wr * 64 + mi * 16 + quad * 4 + r;
      const float val = (acc[mi][ni][r] + bv2) * scale;
      if (mode == 0) {
        out[(size_t)m * 512 + ncol] = (_Float16)val;
      } else {
        const int s = m >> 3, nn = m & 7, h = ncol >> 6, d = ncol & 63;
        out[(size_t)(nn * 8 + h) * 65536 + (size_t)d * 1024 + s] = (_Float16)val;
      }
    }
  }
}

// ---------------------------------------------------------------------------
// K8 (LDS-staged): out0[m,i] = sum_j ctx2[m,j]*Wo[i,j] + bo[i]   (fp32 out)
// ---------------------------------------------------------------------------
__global__ __launch_bounds__(256) void out_gemm(
    const _Float16* __restrict__ X, const float* __restrict__ W,
    const float* __restrict__ bias, float* __restrict__ out)
{
  __shared__ _Float16 As[128][40];
  __shared__ _Float16 Bs[128][40];

  const int tid = threadIdx.x, wave = tid >> 6, lane = tid & 63;
  const int lrow = lane & 15, quad = lane >> 4;
  const int wr = wave >> 1, wc = wave & 1;
  const int m_base = blockIdx.x * 128;
  const int n_base = blockIdx.y * 128;
  const int srow = tid >> 2, scol = (tid & 3) * 8;

  const _Float16* xp0 = X + (size_t)(m_base + srow)      * 512 + scol;
  const _Float16* xp1 = X + (size_t)(m_base + 64 + srow) * 512 + scol;
  const float*    wp0 = W + (size_t)(n_base + srow)      * 512 + scol;
  const float*    wp1 = W + (size_t)(n_base + 64 + srow) * 512 + scol;

  f16x8 ha, hb; f32x4 rc0, rc1, rd0, rd1;
  auto LOADK = [&](int k0) {
    ha  = *(const f16x8*)(xp0 + k0);
    hb  = *(const f16x8*)(xp1 + k0);
    rc0 = *(const f32x4*)(wp0 + k0);  rc1 = *(const f32x4*)(wp0 + k0 + 4);
    rd0 = *(const f32x4*)(wp1 + k0);  rd1 = *(const f32x4*)(wp1 + k0 + 4);
  };

  f32x4 acc[4][4] = {};
  LOADK(0);
  for (int k0 = 0; k0 < 512; k0 += 32) {
    __syncthreads();
    *(f16x8*)&As[srow][scol]      = ha;
    *(f16x8*)&As[srow + 64][scol] = hb;
    *(f16x8*)&Bs[srow][scol]      = cvt8(rc0, rc1);
    *(f16x8*)&Bs[srow + 64][scol] = cvt8(rd0, rd1);
    __syncthreads();
    if (k0 + 32 < 512) LOADK(k0 + 32);
    f16x8 af[4], bf[4];
#pragma unroll
    for (int mi = 0; mi < 4; ++mi)
      af[mi] = *(const f16x8*)&As[wr * 64 + mi * 16 + lrow][quad * 8];
#pragma unroll
    for (int ni = 0; ni < 4; ++ni)
      bf[ni] = *(const f16x8*)&Bs[wc * 64 + ni * 16 + lrow][quad * 8];
#pragma unroll
    for (int mi = 0; mi < 4; ++mi)
#pragma unroll
      for (int ni = 0; ni < 4; ++ni)
        acc[mi][ni] = MFMA_F16(af[mi], bf[ni], acc[mi][ni], 0, 0, 0);
  }

#pragma unroll
  for (int mi = 0; mi < 4; ++mi)
#pragma unroll
  for (int ni = 0; ni < 4; ++ni) {
    const int ncol = n_base + wc * 64 + ni * 16 + lrow;
    const float bv2 = bias[ncol];
#pragma unroll
    for (int r = 0; r < 4; ++r) {
      const int m = m_base + wr * 64 + mi * 16 + quad * 4 + r;
      out[(size_t)m * 512 + ncol] = acc[mi][ni][r] + bv2;
    }
  }
}

// ---------------------------------------------------------------------------
// K2: content scores per b: sbuf[l][b][s] = sum_d q[l,b,d]*k[s,b,d]
// WRITE-ONLY into [l][b][s] layout (pos term added in fused kernel).
// ---------------------------------------------------------------------------
__global__ __launch_bounds__(256) void qk_content(
    const _Float16* __restrict__ qb, const _Float16* __restrict__ kb,
    _Float16* __restrict__ sbuf)
{
  const int b = blockIdx.z;
  const int tid = threadIdx.x, wave = tid >> 6, lane = tid & 63;
  const int lrow = lane & 15, quad = lane >> 4;
  const int l_base = blockIdx.x * 64 + (wave >> 1) * 32;
  const int s_base = blockIdx.y * 64 + (wave & 1) * 32;
  const _Float16* qp = qb + b * 64;
  const _Float16* kp = kb + b * 64;
  f32x4 acc[2][2] = {};
#pragma unroll
  for (int k0 = 0; k0 < 64; k0 += 32) {
    const int ko = k0 + quad * 8;
    f16x8 a0 = *(const f16x8*)(qp + (size_t)(l_base + lrow) * 4096 + ko);
    f16x8 a1 = *(const f16x8*)(qp + (size_t)(l_base + 16 + lrow) * 4096 + ko);
    f16x8 b0 = *(const f16x8*)(kp + (size_t)(s_base + lrow) * 4096 + ko);
    f16x8 b1 = *(const f16x8*)(kp + (size_t)(s_base + 16 + lrow) * 4096 + ko);
    acc[0][0] = MFMA_F16(a0, b0, acc[0][0], 0, 0, 0);
    acc[0][1] = MFMA_F16(a0, b1, acc[0][1], 0, 0, 0);
    acc[1][0] = MFMA_F16(a1, b0, acc[1][0], 0, 0, 0);
    acc[1][1] = MFMA_F16(a1, b1, acc[1][1], 0, 0, 0);
  }
  _Float16* sp = sbuf + (size_t)b * 1024;
#pragma unroll
  for (int i = 0; i < 2; ++i)
#pragma unroll
  for (int j = 0; j < 2; ++j)
#pragma unroll
  for (int r = 0; r < 4; ++r) {
    const size_t idx = (size_t)(l_base + i * 16 + quad * 4 + r) * 65536 +
                       s_base + j * 16 + lrow;
    sp[idx] = (_Float16)acc[i][j][r];
  }
}

// ---------------------------------------------------------------------------
// K3+K4 fused: per l (one block, 512 thr, 8 waves):
//   x[b,s] = sbuf[l][b][s] + sum_d q[l,b,d]*pos_k[l,s,d]
//   w = softmax_s(x) -> sbuf[l][b][s] fp16 ;  avg over heads -> avg_out
// Wave w owns s-strip [w*128, (w+1)*128): 8 s-tiles x 4 b-chunks.
// Content scores loaded as MFMA C-in (fused add). Softmax: in-lane +
// shfl_xor(16,32) + LDS combine over 8 waves. Head-avg: shfl_xor(1,2,4).
// pos_k[l] read exactly once per l.
// ---------------------------------------------------------------------------
__global__ __launch_bounds__(512) void pos_softmax_avg(
    const _Float16* __restrict__ qb, const float* __restrict__ pk,
    _Float16* __restrict__ sbuf, float* __restrict__ avg_out)
{
  __shared__ float pmax[8][64];
  __shared__ float psum[8][64];

  const int l = blockIdx.x;
  const int tid = threadIdx.x, wave = tid >> 6, lane = tid & 63;
  const int lrow = lane & 15, quad = lane >> 4;
  const int s_base = wave * 128;

  const _Float16* qp = qb + (size_t)l * 4096;
  const float*    pp = pk + (size_t)l * 65536 + (size_t)s_base * 64;
  _Float16*       sp = sbuf + (size_t)l * 65536;

  // B fragments: q rows for all 4 b-chunks (constant over the s loop)
  f16x8 bq[4][2];
#pragma unroll
  for (int bc = 0; bc < 4; ++bc)
#pragma unroll
    for (int ks = 0; ks < 2; ++ks)
      bq[bc][ks] = *(const f16x8*)(qp + (size_t)(bc * 16 + lrow) * 64 + ks * 32 + quad * 8);

  // init acc with content scores (MFMA C-in): lane (b=bc*16+lrow,
  // s=s_base+t*16+quad*4+r)
  f32x4 acc[8][4];
#pragma unroll
  for (int t = 0; t < 8; ++t)
#pragma unroll
    for (int bc = 0; bc < 4; ++bc) {
      const f16x4 c = *(const f16x4*)(sp + (size_t)(bc * 16 + lrow) * 1024 +
                                      s_base + t * 16 + quad * 4);
#pragma unroll
      for (int r = 0; r < 4; ++r) acc[t][bc][r] = (float)c[r];
    }

  // pos scores: stream pos_k rows once; A reused across the 4 b-chunks
#pragma unroll
  for (int t = 0; t < 8; ++t) {
#pragma unroll
    for (int ks = 0; ks < 2; ++ks) {
      const f16x8 a = ld8f(pp + (size_t)(t * 16 + lrow) * 64 + ks * 32 + quad * 8);
#pragma unroll
      for (int bc = 0; bc < 4; ++bc)
        acc[t][bc] = MFMA_F16(a, bq[bc][ks], acc[t][bc], 0, 0, 0);
    }
  }

  // wave-partial max/sum over this strip's 128 s per b-column
  float mw[4], zw[4];
#pragma unroll
  for (int bc = 0; bc < 4; ++bc) {
    float m = acc[0][bc][0];
#pragma unroll
    for (int t = 0; t < 8; ++t)
#pragma unroll
      for (int r = 0; r < 4; ++r) m = fmaxf(m, acc[t][bc][r]);
    m = fmaxf(m, __shfl_xor(m, 16));
    m = fmaxf(m, __shfl_xor(m, 32));
    float z = 0.f;
#pragma unroll
    for (int t = 0; t < 8; ++t)
#pragma unroll
      for (int r = 0; r < 4; ++r) { acc[t][bc][r] = __expf(acc[t][bc][r] - m); z += acc[t][bc][r]; }
    z += __shfl_xor(z, 16);
    z += __shfl_xor(z, 32);
    mw[bc] = m; zw[bc] = z;
  }

  if (lane < 16) {
#pragma unroll
    for (int bc = 0; bc < 4; ++bc) {
      pmax[wave][bc * 16 + lrow] = mw[bc];
      psum[wave][bc * 16 + lrow] = zw[bc];
    }
  }
  __syncthreads();

  // global max / sum across the 8 s-strips; per-lane scale for its b
  float scl[4];
#pragma unroll
  for (int bc = 0; bc < 4; ++bc) {
    const int b = bc * 16 + lrow;
    float M = pmax[0][b];
#pragma unroll
    for (int o = 1; o < 8; ++o) M = fmaxf(M, pmax[o][b]);
    float Z = 0.f;
#pragma unroll
    for (int o = 0; o < 8; ++o) Z += psum[o][b] * __expf(pmax[o][b] - M);
    scl[bc] = __expf(mw[bc] - M) / Z;
  }

  // normalize, write w fp16 back; head-avg via shfl over b-octet
  const bool wr_avg = ((lane & 7) == 0);
#pragma unroll
  for (int t = 0; t < 8; ++t) {
#pragma unroll
    for (int bc = 0; bc < 4; ++bc) {
      f16x4 wv; f32x4 av;
#pragma unroll
      for (int r = 0; r < 4; ++r) {
        const float w = acc[t][bc][r] * scl[bc];
        wv[r] = (_Float16)w;
        float hsum = w;
        hsum += __shfl_xor(hsum, 1);
        hsum += __shfl_xor(hsum, 2);
        hsum += __shfl_xor(hsum, 4);
        av[r] = hsum * 0.125f;
      }
      *(f16x4*)(sp + (size_t)(bc * 16 + lrow) * 1024 + s_base + t * 16 + quad * 4) = wv;
      if (wr_avg) {
        const int n = (bc * 16 + lrow) >> 3;
        *(f32x4*)(avg_out + (size_t)n * 1048576 + (size_t)l * 1024 +
                  s_base + t * 16 + quad * 4) = av;
      }
    }
  }
}

// ---------------------------------------------------------------------------
// K6: content PV per b: ctx[l, b*64+d] = sum_s w[l][b][s]*v[b,s,d]  (fp32)
// ---------------------------------------------------------------------------
__global__ __launch_bounds__(256) void pv_content(
    const _Float16* __restrict__ sbuf, const _Float16* __restrict__ vT,
    float* __restrict__ ctx)
{
  const int b = blockIdx.x;
  const int tid = threadIdx.x, wave = tid >> 6, lane = tid & 63;
  const int lrow = lane & 15, quad = lane >> 4;
  const int l_base = blockIdx.y * 64 + (wave >> 1) * 32;
  const int d_base = (wave & 1) * 32;
  const _Float16* wp = sbuf + (size_t)b * 1024;
  const _Float16* vp = vT + (size_t)b * 65536;
  f32x4 acc[2][2] = {};
  for (int s0 = 0; s0 < 1024; s0 += 32) {
    const int so = s0 + quad * 8;
    f16x8 a0 = *(const f16x8*)(wp + (size_t)(l_base + lrow) * 65536 + so);
    f16x8 a1 = *(const f16x8*)(wp + (size_t)(l_base + 16 + lrow) * 65536 + so);
    f16x8 b0 = *(const f16x8*)(vp + (size_t)(d_base + lrow) * 1024 + so);
    f16x8 b1 = *(const f16x8*)(vp + (size_t)(d_base + 16 + lrow) * 1024 + so);
    acc[0][0] = MFMA_F16(a0, b0, acc[0][0], 0, 0, 0);
    acc[0][1] = MFMA_F16(a0, b1, acc[0][1], 0, 0, 0);
    acc[1][0] = MFMA_F16(a1, b0, acc[1][0], 0, 0, 0);
    acc[1][1] = MFMA_F16(a1, b1, acc[1][1], 0, 0, 0);
  }
#pragma unroll
  for (int i = 0; i < 2; ++i)
#pragma unroll
  for (int j = 0; j < 2; ++j)
#pragma unroll
  for (int r = 0; r < 4; ++r)
    ctx[(size_t)(l_base + i * 16 + quad * 4 + r) * 4096 + b * 64 + d_base + j * 16 + lrow] =
        acc[i][j][r];
}

// ---------------------------------------------------------------------------
// K7: pos PV per l: ctx2[l, b*64+d] = fp16(ctx + sum_s w[l][b][s]*pos_v[l,s,d])
// pos_v staged through LDS transposed [d][s] (stride 72).
// ---------------------------------------------------------------------------
__global__ __launch_bounds__(256) void pv_pos(
    const _Float16* __restrict__ sbuf, const float* __restrict__ pv,
    const float* __restrict__ ctx, _Float16* __restrict__ ctx2)
{
  __shared__ _Float16 lds[64][72];
  const int l = blockIdx.x;
  const int tid = threadIdx.x, wave = tid >> 6, lane = tid & 63;
  const int lrow = lane & 15, quad = lane >> 4;
  const int b_base = (wave >> 1) * 32;
  const int d_base = (wave & 1) * 32;
  const float* pp = pv + (size_t)l * 65536;
  const _Float16* wp = sbuf + (size_t)l * 65536;
  const int st_s = tid >> 2, st_d = (tid & 3) * 16;
  f32x4 acc[2][2] = {};
  for (int s0 = 0; s0 < 1024; s0 += 64) {
    __syncthreads();
    const float* src = pp + (size_t)(s0 + st_s) * 64 + st_d;
    const f32x4 va = *(const f32x4*)src;
    const f32x4 vb = *(const f32x4*)(src + 4);
    const f32x4 vc = *(const f32x4*)(src + 8);
    const f32x4 vd = *(const f32x4*)(src + 12);
#pragma unroll
    for (int u = 0; u < 4; ++u) {
      lds[st_d + u     ][st_s] = (_Float16)va[u];
      lds[st_d + u + 4 ][st_s] = (_Float16)vb[u];
      lds[st_d + u + 8 ][st_s] = (_Float16)vc[u];
      lds[st_d + u + 12][st_s] = (_Float16)vd[u];
    }
    __syncthreads();
#pragma unroll
    for (int k0 = 0; k0 < 64; k0 += 32) {
      const int so = s0 + k0 + quad * 8;
      const int sl = k0 + quad * 8;
      f16x8 a0 = *(const f16x8*)(wp + (size_t)(b_base + lrow) * 1024 + so);
      f16x8 a1 = *(const f16x8*)(wp + (size_t)(b_base + 16 + lrow) * 1024 + so);
      f16x8 b0 = *(const f16x8*)(&lds[d_base + lrow][sl]);
      f16x8 b1 = *(const f16x8*)(&lds[d_base + 16 + lrow][sl]);
      acc[0][0] = MFMA_F16(a0, b0, acc[0][0], 0, 0, 0);
      acc[0][1] = MFMA_F16(a0, b1, acc[0][1], 0, 0, 0);
      acc[1][0] = MFMA_F16(a1, b0, acc[1][0], 0, 0, 0);
      acc[1][1] = MFMA_F16(a1, b1, acc[1][1], 0, 0, 0);
    }
  }
#pragma unroll
  for (int i = 0; i < 2; ++i)
#pragma unroll
  for (int j = 0; j < 2; ++j)
#pragma unroll
  for (int r = 0; r < 4; ++r) {
    const size_t idx = (size_t)l * 4096 + (size_t)(b_base + i * 16 + quad * 4 + r) * 64 +
                       d_base + j * 16 + lrow;
    ctx2[idx] = (_Float16)(ctx[idx] + acc[i][j][r]);
  }
}

// ---------------------------------------------------------------------------
extern "C" void kernel_launch(void* const* d_in, const int* in_sizes, int n_in,
                              void* d_out, int out_size, void* d_ws, size_t ws_size,
                              hipStream_t stream)
{
  const float* query = (const float*)d_in[0];
  const float* key   = (const float*)d_in[1];
  const float* value = (const float*)d_in[2];
  const float* pos_k = (const float*)d_in[3];
  const float* pos_v = (const float*)d_in[4];
  const float* Wq = (const float*)d_in[5];
  const float* bq = (const float*)d_in[6];
  const float* Wk = (const float*)d_in[7];
  const float* bk = (const float*)d_in[8];
  const float* Wv = (const float*)d_in[9];
  const float* bv = (const float*)d_in[10];
  const float* Wo = (const float*)d_in[11];
  const float* bo = (const float*)d_in[12];

  char* ws = (char*)d_ws;
  _Float16* qb   = (_Float16*)(ws);                        // 8 MiB  [l][b*64+d]
  _Float16* kb   = (_Float16*)(ws + (size_t)(8u  << 20));  // 8 MiB  [s][b*64+d]
  _Float16* vT   = (_Float16*)(ws + (size_t)(16u << 20));  // 8 MiB  [b][d][s]
  _Float16* sbuf = (_Float16*)(ws + (size_t)(24u << 20));  // 128 MiB [l][b][s]
  float*    ctx  = (float*)   (ws + (size_t)(152u << 20)); // 16 MiB [l][b*64+d]
  _Float16* ctx2 = (_Float16*)(ws + (size_t)(168u << 20)); // 8 MiB  [l][b*64+d]

  float* out0 = (float*)d_out;
  float* avg  = out0 + (size_t)4194304;

  dim3 blk(256);
  proj_all<<<dim3(64, 4, 3), blk, 0, stream>>>(query, key, value,
                                               Wq, Wk, Wv, bq, bk, bv,
                                               qb, kb, vT);
  qk_content<<<dim3(16, 16, 64), blk, 0, stream>>>(qb, kb, sbuf);       // write
  pos_softmax_avg<<<dim3(1024), dim3(512), 0, stream>>>(qb, pos_k, sbuf, avg);
  pv_content<<<dim3(64, 16), blk, 0, stream>>>(sbuf, vT, ctx);
  pv_pos<<<dim3(1024), blk, 0, stream>>>(sbuf, pos_v, ctx, ctx2);
  out_gemm<<<dim3(64, 4), blk, 0, stream>>>(ctx2, Wo, bo, out0);
}